// Round 1
// baseline (1086.719 us; speedup 1.0000x reference)
//
#include <hip/hip_runtime.h>
#include <stdint.h>

// Problem constants (B=8, N=4096, S=1024 queries/batch, K=32 neighbors)
#define TOT   262144      // 8*1024*32 grouped elements
#define NPTS  4096
#define KNN   32
#define BN_EPS 1e-5f
#define NBLK  512         // stats/layer kernels: 512 blocks x 256 thr, 2 elems/thr

__device__ __forceinline__ float wsumf(float v){
  #pragma unroll
  for (int off=32; off; off>>=1) v += __shfl_xor(v, off, 64);
  return v;
}
__device__ __forceinline__ int wsumi(int v){
  #pragma unroll
  for (int off=32; off; off>>=1) v += __shfl_xor(v, off, 64);
  return v;
}
__device__ __forceinline__ int mbcnt64(unsigned long long m){
  return __builtin_amdgcn_mbcnt_hi((unsigned)(m>>32),
         __builtin_amdgcn_mbcnt_lo((unsigned)(m & 0xffffffffull), 0));
}
// monotone float -> uint key (handles the tiny-negative rounding case)
__device__ __forceinline__ unsigned f2ord(float f){
  unsigned u = __float_as_uint(f);
  return (u & 0x80000000u) ? ~u : (u | 0x80000000u);
}

// K1: one wave per query. Exact 32-NN via 32-bit radix bisection for the
// 32nd-smallest key, then ballot/prefix collection (index-ascending ties,
// matching jax.lax.top_k stability). Writes new_xyz and gathered/centered
// features SoA: grouped[c*TOT + q*32 + slot], c: 0-2 = xyz-q, 3-8 = points.
__global__ __launch_bounds__(256) void knn_gather(
    const float* __restrict__ xyz, const float* __restrict__ pts,
    float* __restrict__ grouped, float* __restrict__ out_newxyz){
  const int lane = threadIdx.x & 63;
  const int q = blockIdx.x*4 + (threadIdx.x>>6);     // 0..8191
  const int b = q >> 10, s = q & 1023;
  const float* xb = xyz + (size_t)b*NPTS*3;
  const int nq = s*4;                                 // stride = 4096/1024
  const float qx = xb[nq*3+0], qy = xb[nq*3+1], qz = xb[nq*3+2];
  const float qq = qx*qx + qy*qy + qz*qz;
  if (lane < 3) out_newxyz[q*3+lane] = (lane==0)?qx:((lane==1)?qy:qz);

  unsigned key[64];
  #pragma unroll
  for (int j=0;j<64;j++){
    int n = j*64 + lane;
    float px = xb[n*3+0], py = xb[n*3+1], pz = xb[n*3+2];
    float d = qq + (px*px+py*py+pz*pz) - 2.0f*(qx*px + qy*py + qz*pz);
    key[j] = f2ord(d);
  }
  // V = 32nd smallest key (1-indexed), exact
  unsigned P = 0;
  for (int bit=31; bit>=0; --bit){
    unsigned X = P | (1u<<bit);
    int c = 0;
    #pragma unroll
    for (int j=0;j<64;j++) c += (key[j] < X) ? 1 : 0;
    c = wsumi(c);
    if (__builtin_amdgcn_readfirstlane(c) < KNN) P = X;
  }
  // collect: all keys < V, then keys == V in ascending index until 32 filled
  const float* pb = pts + (size_t)b*NPTS*6;
  const int e_base = q*KNN;
  int cnt = 0;                                        // wave-uniform
  #pragma unroll 1
  for (int pass=0; pass<2; ++pass){
    #pragma unroll
    for (int j=0;j<64;j++){
      bool sel = (pass==0) ? (key[j] < P) : (key[j] == P);
      unsigned long long m = __ballot(sel);
      int pos = cnt + mbcnt64(m);
      if (sel && pos < KNN){
        int n = j*64 + lane;
        int e = e_base + pos;
        float px = xb[n*3+0], py = xb[n*3+1], pz = xb[n*3+2];
        grouped[0*TOT+e] = px - qx;
        grouped[1*TOT+e] = py - qy;
        grouped[2*TOT+e] = pz - qz;
        #pragma unroll
        for (int c6=0;c6<6;c6++) grouped[(3+c6)*TOT+e] = pb[n*6+c6];
      }
      cnt += __popcll(m);
    }
  }
}

// K2: accumulate E[g] (9) and E[g g^T] upper triangle (45) partials.
__global__ __launch_bounds__(256) void stats0(
    const float* __restrict__ grouped, float* __restrict__ partial0){
  const int tid = threadIdx.x, lane = tid&63, wv = tid>>6;
  float v[54];
  #pragma unroll
  for (int i=0;i<54;i++) v[i]=0.f;
  #pragma unroll 1
  for (int it=0; it<2; ++it){
    int n = it*(NBLK*256) + blockIdx.x*256 + tid;
    float g[9];
    #pragma unroll
    for (int c=0;c<9;c++) g[c] = grouped[c*TOT+n];
    #pragma unroll
    for (int c=0;c<9;c++) v[c] += g[c];
    int t=9;
    #pragma unroll
    for (int c=0;c<9;c++)
      #pragma unroll
      for (int c2=0;c2<=c;c2++){ v[t] += g[c]*g[c2]; t++; }
  }
  __shared__ float lds[4][54];
  #pragma unroll
  for (int i=0;i<54;i++){
    float r = wsumf(v[i]);
    if (lane==0) lds[wv][i]=r;
  }
  __syncthreads();
  if (tid < 54) partial0[blockIdx.x*54+tid] =
      lds[0][tid]+lds[1][tid]+lds[2][tid]+lds[3][tid];
}

// K3: stats0 -> folded BN0 coeffs a0[64], c0[64] (bn(x)=x*a+c)
__global__ void finalize0(const float* __restrict__ partial0,
    const float* __restrict__ W0, const float* __restrict__ g0,
    const float* __restrict__ b0, float* __restrict__ ac0){
  const int tid = threadIdx.x;
  __shared__ float S[54];
  if (tid < 54){
    float a=0.f;
    for (int bk=0;bk<NBLK;bk++) a += partial0[bk*54+tid];
    S[tid]=a;
  }
  __syncthreads();
  if (tid < 64){
    float w[9];
    #pragma unroll
    for (int c=0;c<9;c++) w[c]=W0[tid*9+c];
    float m=0.f;
    #pragma unroll
    for (int c=0;c<9;c++) m += w[c]*S[c];
    float e2=0.f; int t=9;
    #pragma unroll
    for (int c=0;c<9;c++)
      #pragma unroll
      for (int c2=0;c2<=c;c2++){
        float x = w[c]*w[c2]*S[t++];
        e2 += (c2==c) ? x : 2.f*x;
      }
    const float inv = 1.f/(float)TOT;
    m *= inv; e2 *= inv;
    float var = e2 - m*m;
    float a = g0[tid]*rsqrtf(var + BN_EPS);
    ac0[tid]    = a;
    ac0[64+tid] = fmaf(-m, a, b0[tid]);
  }
}

// K4: recompute x0, bn0+relu, x1 = h0 @ W1^T; store x1 SoA; channel sums.
__global__ __launch_bounds__(256) void layer1(
    const float* __restrict__ grouped, const float* __restrict__ W0,
    const float* __restrict__ W1, const float* __restrict__ ac0,
    float* __restrict__ x1ws, float* __restrict__ partial1){
  const int tid = threadIdx.x, lane = tid&63, wv = tid>>6;
  float accS=0.f, accQ=0.f;
  #pragma unroll 1
  for (int it=0; it<2; ++it){
    int n = it*(NBLK*256) + blockIdx.x*256 + tid;
    float g[9];
    #pragma unroll
    for (int c=0;c<9;c++) g[c]=grouped[c*TOT+n];
    float h0[64];
    #pragma unroll
    for (int o=0;o<64;o++){
      float a=0.f;
      #pragma unroll
      for (int c=0;c<9;c++) a = fmaf(g[c], W0[o*9+c], a);
      h0[o] = fmaxf(fmaf(a, ac0[o], ac0[64+o]), 0.f);
    }
    #pragma unroll 1
    for (int o=0;o<64;o++){
      const float* wr = W1 + o*64;
      float a0=0.f,a1=0.f,a2=0.f,a3=0.f;
      #pragma unroll
      for (int c=0;c<64;c+=4){
        a0=fmaf(h0[c  ],wr[c  ],a0); a1=fmaf(h0[c+1],wr[c+1],a1);
        a2=fmaf(h0[c+2],wr[c+2],a2); a3=fmaf(h0[c+3],wr[c+3],a3);
      }
      float x = (a0+a1)+(a2+a3);
      x1ws[(size_t)o*TOT+n] = x;
      float rs = wsumf(x), rq = wsumf(x*x);
      bool mine = (lane==o);
      accS += mine ? rs : 0.f;
      accQ += mine ? rq : 0.f;
    }
  }
  __shared__ float lds[4][128];
  lds[wv][lane]    = accS;
  lds[wv][64+lane] = accQ;
  __syncthreads();
  if (tid < 128) partial1[blockIdx.x*128+tid] =
      lds[0][tid]+lds[1][tid]+lds[2][tid]+lds[3][tid];
}

// K5/K7: reduce channel partials -> folded BN coeffs (a then c)
__global__ void finalize12(const float* __restrict__ partial, int nblk, int nch,
    const float* __restrict__ gg, const float* __restrict__ bb,
    float* __restrict__ ac){
  const int tid = threadIdx.x;
  __shared__ float S[256];
  if (tid < 2*nch){
    float a=0.f;
    for (int bk=0;bk<nblk;bk++) a += partial[bk*2*nch+tid];
    S[tid]=a;
  }
  __syncthreads();
  if (tid < nch){
    const float inv = 1.f/(float)TOT;
    float m = S[tid]*inv;
    float v = S[nch+tid]*inv - m*m;
    float a = gg[tid]*rsqrtf(v + BN_EPS);
    ac[tid]     = a;
    ac[nch+tid] = fmaf(-m, a, bb[tid]);
  }
}

// K6: bn1+relu, x2 = h1 @ W2^T; channel sums; max over k=32 (lanes share
// query in 32-groups). BN2+relu applied AFTER max (a2>0, monotone).
__global__ __launch_bounds__(256) void layer2max(
    const float* __restrict__ x1ws, const float* __restrict__ W2,
    const float* __restrict__ ac1, float* __restrict__ maxbuf,
    float* __restrict__ partial2){
  const int tid = threadIdx.x, lane = tid&63, wv = tid>>6;
  float sA=0.f,qA=0.f,sB=0.f,qB=0.f;
  #pragma unroll 1
  for (int it=0; it<2; ++it){
    int n = it*(NBLK*256) + blockIdx.x*256 + tid;
    int qrow = n >> 5;
    float h1[64];
    #pragma unroll
    for (int c=0;c<64;c++){
      float x = x1ws[(size_t)c*TOT+n];
      h1[c] = fmaxf(fmaf(x, ac1[c], ac1[64+c]), 0.f);
    }
    #pragma unroll 1
    for (int o=0;o<128;o++){
      const float* wr = W2 + o*64;
      float a0=0.f,a1=0.f,a2=0.f,a3=0.f;
      #pragma unroll
      for (int c=0;c<64;c+=4){
        a0=fmaf(h1[c  ],wr[c  ],a0); a1=fmaf(h1[c+1],wr[c+1],a1);
        a2=fmaf(h1[c+2],wr[c+2],a2); a3=fmaf(h1[c+3],wr[c+3],a3);
      }
      float x = (a0+a1)+(a2+a3);
      float rs = wsumf(x), rq = wsumf(x*x);
      bool mine = (lane == (o&63));
      if (o < 64){ sA += mine?rs:0.f; qA += mine?rq:0.f; }
      else       { sB += mine?rs:0.f; qB += mine?rq:0.f; }
      float mx = x;
      #pragma unroll
      for (int off=16; off; off>>=1) mx = fmaxf(mx, __shfl_xor(mx, off, 64));
      if ((lane&31)==0) maxbuf[(size_t)qrow*128+o] = mx;
    }
  }
  __shared__ float lds[4][256];
  lds[wv][lane]      = sA;   // ch = lane        (sums 0..63)
  lds[wv][64+lane]   = sB;   // ch = 64+lane     (sums 64..127)
  lds[wv][128+lane]  = qA;   // sq  0..63
  lds[wv][192+lane]  = qB;   // sq  64..127
  __syncthreads();
  if (tid < 256) partial2[blockIdx.x*256+tid] =
      lds[0][tid]+lds[1][tid]+lds[2][tid]+lds[3][tid];
}

// K8: out_newpoints = relu(a2 * max + c2)   (valid since a2 > 0: g2 == 1)
__global__ __launch_bounds__(256) void apply2(
    const float* __restrict__ maxbuf, const float* __restrict__ ac2,
    float* __restrict__ outp){
  int i = blockIdx.x*256 + threadIdx.x;     // 8192*128 = 1048576
  int o = i & 127;
  outp[i] = fmaxf(fmaf(maxbuf[i], ac2[o], ac2[128+o]), 0.f);
}

extern "C" void kernel_launch(void* const* d_in, const int* in_sizes, int n_in,
                              void* d_out, int out_size, void* d_ws, size_t ws_size,
                              hipStream_t stream){
  const float* xyz = (const float*)d_in[0];
  const float* pts = (const float*)d_in[1];
  const float* W0  = (const float*)d_in[2];
  const float* g0  = (const float*)d_in[3];
  const float* b0  = (const float*)d_in[4];
  const float* W1  = (const float*)d_in[5];
  const float* g1  = (const float*)d_in[6];
  const float* b1  = (const float*)d_in[7];
  const float* W2  = (const float*)d_in[8];
  const float* g2  = (const float*)d_in[9];
  const float* b2  = (const float*)d_in[10];
  float* out = (float*)d_out;

  float* ws      = (float*)d_ws;
  float* grouped = ws;                         // 9*TOT        (9.4 MB)
  float* x1ws    = ws + (size_t) 9*TOT;        // 64*TOT       (67 MB)
  float* maxbuf  = ws + (size_t)73*TOT;        // 4*TOT        (4.2 MB)
  float* p0      = ws + (size_t)77*TOT;        // 512*54
  float* p1      = p0 + NBLK*54;               // 512*128
  float* p2      = p1 + NBLK*128;              // 512*256
  float* ac0     = p2 + NBLK*256;              // 128
  float* ac1     = ac0 + 128;                  // 128
  float* ac2     = ac1 + 128;                  // 256

  knn_gather<<<2048, 256, 0, stream>>>(xyz, pts, grouped, out);
  stats0    <<<NBLK, 256, 0, stream>>>(grouped, p0);
  finalize0 <<<1,     64, 0, stream>>>(p0, W0, g0, b0, ac0);
  layer1    <<<NBLK, 256, 0, stream>>>(grouped, W0, W1, ac0, x1ws, p1);
  finalize12<<<1,    128, 0, stream>>>(p1, NBLK,  64, g1, b1, ac1);
  layer2max <<<NBLK, 256, 0, stream>>>(x1ws, W2, ac1, maxbuf, p2);
  finalize12<<<1,    256, 0, stream>>>(p2, NBLK, 128, g2, b2, ac2);
  apply2    <<<4096, 256, 0, stream>>>(maxbuf, ac2, out + 24576);
}

// Round 2
// 433.221 us; speedup vs baseline: 2.5085x; 2.5085x over previous
//
#include <hip/hip_runtime.h>
#include <float.h>
#include <stdint.h>

// B=8, N=4096, S=1024 queries/batch, K=32 neighbors
#define TOT   262144      // 8*1024*32 grouped elements
#define NPTS  4096
#define KNN   32
#define BN_EPS 1e-5f
#define CAP   512         // kNN candidate capacity per wave (fallback if exceeded)

__device__ __forceinline__ int mbcnt64(unsigned long long m){
  return __builtin_amdgcn_mbcnt_hi((unsigned)(m>>32),
         __builtin_amdgcn_mbcnt_lo((unsigned)(m & 0xffffffffull), 0));
}
// monotone float -> uint key (ascending order preserved)
__device__ __forceinline__ unsigned f2ord(float f){
  unsigned u = __float_as_uint(f);
  return u ^ (((unsigned)((int)u >> 31)) | 0x80000000u);
}

// P0: xyz -> float4 {x,y,z,|p|^2} SoA per point (coalesced distance loads later)
__global__ __launch_bounds__(256) void prep(const float* __restrict__ xyz,
    float4* __restrict__ xyzp){
  int p = blockIdx.x*256 + threadIdx.x;            // 32768 points
  float x = xyz[p*3+0], y = xyz[p*3+1], z = xyz[p*3+2];
  xyzp[p] = make_float4(x, y, z, x*x+y*y+z*z);
}

// K1: one wave per query. Per-lane min -> ballot-bisect 32nd-of-minima = U
// (upper bound of true k32) -> compact keys<=U to LDS -> exact bisect+collect.
// Ties at the threshold resolved by ascending index (jax.lax.top_k semantics).
__global__ __launch_bounds__(256) void knn_gather(
    const float4* __restrict__ xyzp, const float* __restrict__ pts,
    float* __restrict__ grouped, float* __restrict__ out_newxyz){
  __shared__ unsigned ckey[4*CAP];
  __shared__ unsigned short cidx[4*CAP];
  const int lane = threadIdx.x & 63;
  const int wv   = threadIdx.x >> 6;
  const int q = blockIdx.x*4 + wv;                 // 0..8191
  const int b = q >> 10, s = q & 1023;
  const float4* xb = xyzp + b*NPTS;
  const int nq = s*4;                              // stride 4096/1024
  const float4 Q = xb[nq];
  const float qx=Q.x, qy=Q.y, qz=Q.z, qq=Q.w;
  if (lane==0){ out_newxyz[q*3]=qx; out_newxyz[q*3+1]=qy; out_newxyz[q*3+2]=qz; }

  unsigned key[64];
  unsigned mm0=0xFFFFFFFFu, mm1=0xFFFFFFFFu, mm2=0xFFFFFFFFu, mm3=0xFFFFFFFFu;
  #pragma unroll
  for (int j=0;j<64;j++){
    int n = j*64 + lane;
    float4 P = xb[n];
    float d = (qq + P.w) - 2.0f*(qx*P.x + qy*P.y + qz*P.z);
    unsigned k = f2ord(d);
    key[j] = k;
    if ((j&3)==0){ if (k<mm0) mm0=k; } else if ((j&3)==1){ if (k<mm1) mm1=k; }
    else if ((j&3)==2){ if (k<mm2) mm2=k; } else { if (k<mm3) mm3=k; }
  }
  unsigned m = mm0<mm1?mm0:mm1; unsigned m2 = mm2<mm3?mm2:mm3;
  if (m2<m) m=m2;

  // U = 32nd smallest of the 64 per-lane minima (>= true 32nd distance key)
  unsigned U=0;
  for (int bit=31; bit>=0; --bit){
    unsigned X = U | (1u<<bit);
    int c = __popcll(__ballot(m < X));
    if (c < KNN) U = X;
  }

  // compact candidates key<=U into per-wave LDS region (ascending index order)
  unsigned* wk = ckey + wv*CAP;
  unsigned short* wi = cidx + wv*CAP;
  int cnt = 0;
  #pragma unroll
  for (int j=0;j<64;j++){
    bool sel = key[j] <= U;
    unsigned long long msk = __ballot(sel);
    int pos = cnt + mbcnt64(msk);
    if (sel && pos < CAP){ wk[pos]=key[j]; wi[pos]=(unsigned short)(j*64+lane); }
    cnt += __popcll(msk);
  }

  const float* fb = pts + (size_t)b*NPTS*6;
  const int ebase = q*KNN;

  if (cnt <= CAP){
    const int nc = (cnt+63)>>6;                    // chunks (typically 1)
    unsigned myk = (lane<cnt) ? wk[lane] : 0xFFFFFFFFu;
    unsigned V=0;
    for (int bit=31; bit>=0; --bit){
      unsigned X = V | (1u<<bit);
      int c = __popcll(__ballot(myk < X));
      for (int ch=1; ch<nc; ++ch){
        int ii = ch*64+lane;
        unsigned kk = (ii<cnt) ? wk[ii] : 0xFFFFFFFFu;
        c += __popcll(__ballot(kk < X));
      }
      if (c < KNN) V = X;
    }
    int cnt2=0;
    for (int pass=0; pass<2; ++pass){
      for (int ch=0; ch<nc; ++ch){
        int ii = ch*64+lane;
        unsigned kk = (ch==0) ? myk : ((ii<cnt) ? wk[ii] : 0xFFFFFFFFu);
        bool sel = pass ? (kk==V) : (kk<V);
        unsigned long long msk = __ballot(sel);
        int pos = cnt2 + mbcnt64(msk);
        if (sel && pos < KNN){
          int n = wi[ii];
          float4 P = xb[n];
          int e = ebase + pos;
          grouped[0*TOT+e]=P.x-qx; grouped[1*TOT+e]=P.y-qy; grouped[2*TOT+e]=P.z-qz;
          #pragma unroll
          for (int c6=0;c6<6;c6++) grouped[(3+c6)*TOT+e]=fb[n*6+c6];
        }
        cnt2 += __popcll(msk);
      }
    }
  } else {
    // fallback: exact select over all 4096 keys (rare)
    unsigned V=0;
    for (int bit=31; bit>=0; --bit){
      unsigned X = V | (1u<<bit);
      int c=0;
      #pragma unroll
      for (int j=0;j<64;j++) c += __popcll(__ballot(key[j] < X));
      if (c < KNN) V = X;
    }
    int cnt2=0;
    for (int pass=0; pass<2; ++pass){
      #pragma unroll
      for (int j=0;j<64;j++){
        bool sel = pass ? (key[j]==V) : (key[j]<V);
        unsigned long long msk = __ballot(sel);
        int pos = cnt2 + mbcnt64(msk);
        if (sel && pos < KNN){
          int n = j*64+lane, e = ebase+pos;
          float4 P = xb[n];
          grouped[0*TOT+e]=P.x-qx; grouped[1*TOT+e]=P.y-qy; grouped[2*TOT+e]=P.z-qz;
          #pragma unroll
          for (int c6=0;c6<6;c6++) grouped[(3+c6)*TOT+e]=fb[n*6+c6];
        }
        cnt2 += __popcll(msk);
      }
    }
  }
}

// K2: E[g](9) + E[g g^T] upper tri (45), atomic-accumulated
__global__ __launch_bounds__(256) void stats0(
    const float* __restrict__ grouped, float* __restrict__ s0g){
  const int tid = threadIdx.x, lane = tid&63, wv = tid>>6;
  float v[54];
  #pragma unroll
  for (int i=0;i<54;i++) v[i]=0.f;
  #pragma unroll 1
  for (int it=0; it<2; ++it){
    int n = it*(512*256) + blockIdx.x*256 + tid;
    float g[9];
    #pragma unroll
    for (int c=0;c<9;c++) g[c] = grouped[c*TOT+n];
    #pragma unroll
    for (int c=0;c<9;c++) v[c] += g[c];
    int t=9;
    #pragma unroll
    for (int c=0;c<9;c++)
      #pragma unroll
      for (int c2=0;c2<=c;c2++){ v[t] += g[c]*g[c2]; t++; }
  }
  __shared__ float lds[4][54];
  #pragma unroll
  for (int i=0;i<54;i++){
    float r = v[i];
    #pragma unroll
    for (int off=32; off; off>>=1) r += __shfl_xor(r, off, 64);
    if (lane==0) lds[wv][i]=r;
  }
  __syncthreads();
  if (tid < 54) atomicAdd(&s0g[tid], lds[0][tid]+lds[1][tid]+lds[2][tid]+lds[3][tid]);
}

// K3: s0g -> folded BN0 coeffs a0[64], c0[64]
__global__ void finalize0(const float* __restrict__ s0g,
    const float* __restrict__ W0, const float* __restrict__ g0,
    const float* __restrict__ b0, float* __restrict__ ac0){
  const int tid = threadIdx.x;
  __shared__ float S[54];
  if (tid < 54) S[tid] = s0g[tid];
  __syncthreads();
  if (tid < 64){
    float w[9];
    #pragma unroll
    for (int c=0;c<9;c++) w[c]=W0[tid*9+c];
    float m=0.f;
    #pragma unroll
    for (int c=0;c<9;c++) m += w[c]*S[c];
    float e2=0.f; int t=9;
    #pragma unroll
    for (int c=0;c<9;c++)
      #pragma unroll
      for (int c2=0;c2<=c;c2++){
        float x = w[c]*w[c2]*S[t++];
        e2 += (c2==c) ? x : 2.f*x;
      }
    const float inv = 1.f/(float)TOT;
    m *= inv; e2 *= inv;
    float var = e2 - m*m;
    float a = g0[tid]*rsqrtf(var + BN_EPS);
    ac0[tid]    = a;
    ac0[64+tid] = fmaf(-m, a, b0[tid]);
  }
}

// K4: x0 -> bn0+relu -> x1 = h0 @ W1^T, stored AoS [n][64]. No inline stats.
__global__ __launch_bounds__(256) void layer1(
    const float* __restrict__ grouped, const float* __restrict__ W0,
    const float* __restrict__ W1, const float* __restrict__ ac0,
    float* __restrict__ x1ws){
  #pragma unroll 1
  for (int it=0; it<2; ++it){
    int n = blockIdx.x*512 + it*256 + threadIdx.x;
    float g[9];
    #pragma unroll
    for (int c=0;c<9;c++) g[c]=grouped[c*TOT+n];
    float h0[64];
    #pragma unroll
    for (int o=0;o<64;o++){
      float a=0.f;
      #pragma unroll
      for (int c=0;c<9;c++) a = fmaf(g[c], W0[o*9+c], a);
      h0[o] = fmaxf(fmaf(a, ac0[o], ac0[64+o]), 0.f);
    }
    float4* outr = (float4*)(x1ws + (size_t)n*64);
    #pragma unroll 1
    for (int o4=0;o4<16;o4++){
      float a0=0.f,a1=0.f,a2=0.f,a3=0.f;
      #pragma unroll
      for (int c=0;c<64;c++){
        a0=fmaf(h0[c],W1[(o4*4+0)*64+c],a0);
        a1=fmaf(h0[c],W1[(o4*4+1)*64+c],a1);
        a2=fmaf(h0[c],W1[(o4*4+2)*64+c],a2);
        a3=fmaf(h0[c],W1[(o4*4+3)*64+c],a3);
      }
      outr[o4]=make_float4(a0,a1,a2,a3);
    }
  }
}

// K5: streaming per-channel sum/sumsq of x1 (AoS), atomic into s1g[128]
__global__ __launch_bounds__(256) void stats1(const float* __restrict__ x1ws,
    float* __restrict__ s1g){
  const int tid=threadIdx.x;
  float acc[8];
  #pragma unroll
  for (int i=0;i<8;i++) acc[i]=0.f;
  const float4* p = (const float4*)x1ws;
  int base = blockIdx.x*256 + tid;                 // grid 512; 32 iters; stride 131072
  #pragma unroll 1
  for (int r=0;r<32;r++){
    float4 v = p[base + r*131072];
    acc[0]+=v.x; acc[1]+=v.y; acc[2]+=v.z; acc[3]+=v.w;
    acc[4]=fmaf(v.x,v.x,acc[4]); acc[5]=fmaf(v.y,v.y,acc[5]);
    acc[6]=fmaf(v.z,v.z,acc[6]); acc[7]=fmaf(v.w,v.w,acc[7]);
  }
  __shared__ float lds[256][8];
  #pragma unroll
  for (int i=0;i<8;i++) lds[tid][i]=acc[i];
  __syncthreads();
  if (tid < 128){
    int c = tid & 63;
    int off = (tid>>6)*4;                          // 0: sum, 4: sumsq
    float v=0.f;
    #pragma unroll
    for (int k=0;k<16;k++) v += lds[(c>>2)+k*16][off + (c&3)];
    atomicAdd(&s1g[(tid>>6)*64 + c], v);
  }
}

// generic: channel sums[nch]+sumsq[nch] -> folded BN coeffs
__global__ void finalizeS(const float* __restrict__ sums, int nch,
    const float* __restrict__ gg, const float* __restrict__ bb,
    float* __restrict__ ac){
  int t=threadIdx.x;
  if (t<nch){
    const float inv=1.f/(float)TOT;
    float m=sums[t]*inv;
    float v=sums[nch+t]*inv - m*m;
    float a=gg[t]*rsqrtf(v+BN_EPS);
    ac[t]=a; ac[nch+t]=fmaf(-m,a,bb[t]);
  }
}

// K6: in-place h1 = relu(a1*x1 + c1)
__global__ __launch_bounds__(256) void h1ify(float* __restrict__ x1ws,
    const float* __restrict__ ac1){
  const int tid=threadIdx.x;
  const int cq = tid & 15;
  float4 aq  = ((const float4*)ac1)[cq];
  float4 cv  = ((const float4*)ac1)[16+cq];
  float4* p=(float4*)x1ws;
  int base = blockIdx.x*256+tid;                   // grid 1024; 16 iters; stride 262144
  #pragma unroll 1
  for (int r=0;r<16;r++){
    float4 v=p[base + r*262144];
    v.x=fmaxf(fmaf(v.x,aq.x,cv.x),0.f);
    v.y=fmaxf(fmaf(v.y,aq.y,cv.y),0.f);
    v.z=fmaxf(fmaf(v.z,aq.z,cv.z),0.f);
    v.w=fmaxf(fmaf(v.w,aq.w,cv.w),0.f);
    p[base + r*262144]=v;
  }
}

// K7: x2 = h1 @ W2^T with lane=channel-pair, wave-uniform h1 rows (scalar
// broadcast loads). max over k and sum/sumsq are per-lane -> zero shuffles.
__global__ __launch_bounds__(256) void layer2max(const float* __restrict__ h1,
    const float* __restrict__ W2, float* __restrict__ maxbuf,
    float* __restrict__ s2g){
  const int lane=threadIdx.x&63, wv=threadIdx.x>>6;
  const int q0 = __builtin_amdgcn_readfirstlane((blockIdx.x*4+wv)*4);
  float w2a[64], w2b[64];
  #pragma unroll
  for (int c4=0;c4<16;c4++){
    float4 va = ((const float4*)W2)[lane*16 + c4];
    float4 vb = ((const float4*)W2)[(64+lane)*16 + c4];
    w2a[c4*4+0]=va.x; w2a[c4*4+1]=va.y; w2a[c4*4+2]=va.z; w2a[c4*4+3]=va.w;
    w2b[c4*4+0]=vb.x; w2b[c4*4+1]=vb.y; w2b[c4*4+2]=vb.z; w2b[c4*4+3]=vb.w;
  }
  float sa=0.f, sb=0.f, qa=0.f, qb=0.f;
  #pragma unroll 1
  for (int i=0;i<4;i++){
    int q = q0+i;
    const float4* hrow = (const float4*)(h1 + (size_t)q*2048);   // 32*64
    float mxa=-FLT_MAX, mxb=-FLT_MAX;
    #pragma unroll 1
    for (int k=0;k<32;k++){
      const float4* r = hrow + k*16;
      float a0=0.f,a1=0.f,b0=0.f,b1=0.f;
      #pragma unroll
      for (int c4=0;c4<16;c4++){
        float4 h=r[c4];
        a0=fmaf(h.x,w2a[c4*4+0],a0); b0=fmaf(h.x,w2b[c4*4+0],b0);
        a1=fmaf(h.y,w2a[c4*4+1],a1); b1=fmaf(h.y,w2b[c4*4+1],b1);
        a0=fmaf(h.z,w2a[c4*4+2],a0); b0=fmaf(h.z,w2b[c4*4+2],b0);
        a1=fmaf(h.w,w2a[c4*4+3],a1); b1=fmaf(h.w,w2b[c4*4+3],b1);
      }
      float x=a0+a1, y=b0+b1;
      sa+=x; sb+=y; qa=fmaf(x,x,qa); qb=fmaf(y,y,qb);
      mxa=fmaxf(mxa,x); mxb=fmaxf(mxb,y);
    }
    maxbuf[q*128+lane]=mxa; maxbuf[q*128+64+lane]=mxb;
  }
  __shared__ float lds[4][256];
  lds[wv][lane]=sa; lds[wv][64+lane]=sb; lds[wv][128+lane]=qa; lds[wv][192+lane]=qb;
  __syncthreads();
  const int tid=threadIdx.x;
  float v = lds[0][tid]+lds[1][tid]+lds[2][tid]+lds[3][tid];
  atomicAdd(&s2g[tid], v);   // [0..127]=sums ch0..127, [128..255]=sumsq
}

// K8: out_newpoints = relu(a2*max + c2)   (a2>0 -> commutes with max)
__global__ __launch_bounds__(256) void apply2(
    const float* __restrict__ maxbuf, const float* __restrict__ ac2,
    float* __restrict__ outp){
  int i = blockIdx.x*256 + threadIdx.x;            // 1048576
  int o = i & 127;
  outp[i] = fmaxf(fmaf(maxbuf[i], ac2[o], ac2[128+o]), 0.f);
}

extern "C" void kernel_launch(void* const* d_in, const int* in_sizes, int n_in,
                              void* d_out, int out_size, void* d_ws, size_t ws_size,
                              hipStream_t stream){
  const float* xyz = (const float*)d_in[0];
  const float* pts = (const float*)d_in[1];
  const float* W0  = (const float*)d_in[2];
  const float* g0  = (const float*)d_in[3];
  const float* b0  = (const float*)d_in[4];
  const float* W1  = (const float*)d_in[5];
  const float* g1  = (const float*)d_in[6];
  const float* b1  = (const float*)d_in[7];
  const float* W2  = (const float*)d_in[8];
  const float* g2  = (const float*)d_in[9];
  const float* b2  = (const float*)d_in[10];
  float* out = (float*)d_out;

  float* ws      = (float*)d_ws;
  float* grouped = ws;                          // 9*TOT  SoA
  float* x1ws    = ws + (size_t) 9*TOT;         // 64*TOT AoS [n][64] (x1 -> h1)
  float* maxbuf  = ws + (size_t)73*TOT;         // 4*TOT
  float4* xyzp   = (float4*)(ws + (size_t)77*TOT);          // 32768 float4
  float* s0g     = ws + (size_t)77*TOT + 131072;            // 64 (54 used)
  float* s1g     = s0g + 64;                    // 128
  float* s2g     = s1g + 128;                   // 256
  float* ac0     = s2g + 256;                   // 128
  float* ac1     = ac0 + 128;                   // 128
  float* ac2     = ac1 + 128;                   // 256

  hipMemsetAsync(s0g, 0, (64+128+256)*sizeof(float), stream);
  prep      <<< 128, 256, 0, stream>>>(xyz, xyzp);
  knn_gather<<<2048, 256, 0, stream>>>(xyzp, pts, grouped, out);
  stats0    <<< 512, 256, 0, stream>>>(grouped, s0g);
  finalize0 <<<   1,  64, 0, stream>>>(s0g, W0, g0, b0, ac0);
  layer1    <<< 512, 256, 0, stream>>>(grouped, W0, W1, ac0, x1ws);
  stats1    <<< 512, 256, 0, stream>>>(x1ws, s1g);
  finalizeS <<<   1, 128, 0, stream>>>(s1g,  64, g1, b1, ac1);
  h1ify     <<<1024, 256, 0, stream>>>(x1ws, ac1);
  layer2max <<< 512, 256, 0, stream>>>(x1ws, W2, maxbuf, s2g);
  finalizeS <<<   1, 128, 0, stream>>>(s2g, 128, g2, b2, ac2);
  apply2    <<<4096, 256, 0, stream>>>(maxbuf, ac2, out + 24576);
}

// Round 3
// 342.565 us; speedup vs baseline: 3.1723x; 1.2646x over previous
//
#include <hip/hip_runtime.h>
#include <float.h>
#include <stdint.h>

// B=8, N=4096, S=1024 queries/batch, K=32 neighbors
#define TOT   262144      // 8*1024*32 grouped elements
#define NPTS  4096
#define KNN   32
#define BN_EPS 1e-5f
#define CAPV  64          // fast-path candidate capacity (1 per lane)

typedef _Float16 f16;
typedef _Float16 f16x2 __attribute__((ext_vector_type(2)));
typedef _Float16 f16x8 __attribute__((ext_vector_type(8)));

__device__ __forceinline__ int mbcnt64(unsigned long long m){
  return __builtin_amdgcn_mbcnt_hi((unsigned)(m>>32),
         __builtin_amdgcn_mbcnt_lo((unsigned)(m & 0xffffffffull), 0));
}
// monotone float -> uint key (ascending order preserved)
__device__ __forceinline__ unsigned f2ord(float f){
  unsigned u = __float_as_uint(f);
  return u ^ (((unsigned)((int)u >> 31)) | 0x80000000u);
}
__device__ __forceinline__ float fdot2(f16x2 a, f16x2 b, float c){
#if __has_builtin(__builtin_amdgcn_fdot2)
  return __builtin_amdgcn_fdot2(a, b, c, false);
#else
  return fmaf((float)a[0], (float)b[0], fmaf((float)a[1], (float)b[1], c));
#endif
}

// P0: xyz -> float4 {x,y,z,|p|^2}
__global__ __launch_bounds__(256) void prep(const float* __restrict__ xyz,
    float4* __restrict__ xyzp){
  int p = blockIdx.x*256 + threadIdx.x;            // 32768 points
  float x = xyz[p*3+0], y = xyz[p*3+1], z = xyz[p*3+2];
  xyzp[p] = make_float4(x, y, z, x*x+y*y+z*z);
}

// K1: one wave per query. Pass A: per-lane min over 64 keys -> bitonic sort
// minima -> U = 32nd smallest (upper bound of true 32nd). Pass B: recompute
// keys, compact <=U to LDS. Fast path (cnt<=64): u64 bitonic sort of
// (key,idx) -> lanes 0..31 = exact kNN set (ties by lowest index, matching
// jax.lax.top_k). Slow path (cnt>64, ~0.1% of queries): recompute bisect.
__global__ __launch_bounds__(256) void knn_gather(
    const float4* __restrict__ xyzp, const float* __restrict__ pts,
    float* __restrict__ grouped, float* __restrict__ out_newxyz){
  __shared__ unsigned skey[4*CAPV];
  __shared__ unsigned short sidx[4*CAPV];
  const int lane = threadIdx.x & 63;
  const int wv   = threadIdx.x >> 6;
  const int q = blockIdx.x*4 + wv;                 // 0..8191
  const int b = q >> 10, s = q & 1023;
  const float4* xb = xyzp + b*NPTS;
  const float4 Q = xb[s*4];                        // stride 4096/1024
  const float qx=Q.x, qy=Q.y, qz=Q.z, qq=Q.w;
  if (lane==0){ out_newxyz[q*3]=qx; out_newxyz[q*3+1]=qy; out_newxyz[q*3+2]=qz; }

  // pass A: per-lane min key over this lane's 64 points
  unsigned m = 0xFFFFFFFFu;
  #pragma unroll 8
  for (int j=0;j<64;j++){
    float4 P = xb[j*64+lane];
    float d = (qq+P.w) - 2.f*(qx*P.x+qy*P.y+qz*P.z);
    unsigned k = f2ord(d);
    m = k<m ? k : m;
  }
  // bitonic sort minima ascending across lanes (no scalar-chain bisect)
  unsigned sm = m;
  #pragma unroll
  for (int k=2;k<=64;k<<=1){
    #pragma unroll
    for (int j=k>>1;j>0;j>>=1){
      unsigned o = __shfl_xor(sm, j, 64);
      bool keepmin = (((lane&k)==0) == ((lane&j)==0));
      sm = keepmin ? (sm<o?sm:o) : (sm>o?sm:o);
    }
  }
  const unsigned U = __shfl(sm, 31, 64);           // 32nd smallest minimum

  // pass B: recompute keys, compact candidates key<=U (>=32 guaranteed)
  unsigned* wk = skey + wv*CAPV;
  unsigned short* wi = sidx + wv*CAPV;
  int cnt = 0;
  #pragma unroll 4
  for (int j=0;j<64;j++){
    float4 P = xb[j*64+lane];
    float d = (qq+P.w) - 2.f*(qx*P.x+qy*P.y+qz*P.z);
    unsigned k = f2ord(d);
    bool sel = (k <= U);
    unsigned long long msk = __ballot(sel);
    int pos = cnt + mbcnt64(msk);
    if (sel && pos < CAPV){ wk[pos]=k; wi[pos]=(unsigned short)(j*64+lane); }
    cnt += __popcll(msk);
  }

  const float* fb = pts + (size_t)b*NPTS*6;
  const int ebase = q*KNN;
  int n = -1;

  if (cnt <= CAPV){
    unsigned myk = (lane<cnt) ? wk[lane] : 0xFFFFFFFFu;
    unsigned myi = (lane<cnt) ? wi[lane] : 0u;
    unsigned long long v = (((unsigned long long)myk)<<16) | myi;
    #pragma unroll
    for (int k=2;k<=64;k<<=1){
      #pragma unroll
      for (int j=k>>1;j>0;j>>=1){
        unsigned long long o = __shfl_xor(v, j, 64);
        bool keepmin = (((lane&k)==0) == ((lane&j)==0));
        v = keepmin ? (v<o?v:o) : (v>o?v:o);
      }
    }
    if (lane < KNN) n = (int)(v & 0xffffull);
  } else {
    // slow exact path: recompute bisect + collect (essentially never taken)
    unsigned V=0;
    for (int bit=31; bit>=0; --bit){
      unsigned X = V | (1u<<bit);
      int c=0;
      for (int j=0;j<64;j++){
        float4 P = xb[j*64+lane];
        float d = (qq+P.w) - 2.f*(qx*P.x+qy*P.y+qz*P.z);
        c += __popcll(__ballot(f2ord(d) < X));
      }
      if (c < KNN) V = X;
    }
    int cnt2=0;
    for (int pass=0; pass<2; ++pass){
      for (int j=0;j<64;j++){
        float4 P = xb[j*64+lane];
        float d = (qq+P.w) - 2.f*(qx*P.x+qy*P.y+qz*P.z);
        unsigned kk = f2ord(d);
        bool sel = pass ? (kk==V) : (kk<V);
        unsigned long long msk = __ballot(sel);
        int pos = cnt2 + mbcnt64(msk);
        if (sel && pos < KNN){
          int nn = j*64+lane, e = ebase+pos;
          grouped[0*TOT+e]=P.x-qx; grouped[1*TOT+e]=P.y-qy; grouped[2*TOT+e]=P.z-qz;
          for (int c6=0;c6<6;c6++) grouped[(3+c6)*TOT+e]=fb[nn*6+c6];
        }
        cnt2 += __popcll(msk);
      }
    }
  }
  if (n >= 0){
    float4 P = xb[n];
    int e = ebase + lane;                          // lanes 0..31 -> coalesced
    grouped[0*TOT+e]=P.x-qx; grouped[1*TOT+e]=P.y-qy; grouped[2*TOT+e]=P.z-qz;
    #pragma unroll
    for (int c6=0;c6<6;c6++) grouped[(3+c6)*TOT+e]=fb[n*6+c6];
  }
}

// K2: E[g](9) + E[g g^T] upper tri (45), atomic-accumulated
__global__ __launch_bounds__(256) void stats0(
    const float* __restrict__ grouped, float* __restrict__ s0g){
  const int tid = threadIdx.x, lane = tid&63, wv = tid>>6;
  float v[54];
  #pragma unroll
  for (int i=0;i<54;i++) v[i]=0.f;
  #pragma unroll 1
  for (int it=0; it<2; ++it){
    int n = it*(512*256) + blockIdx.x*256 + tid;
    float g[9];
    #pragma unroll
    for (int c=0;c<9;c++) g[c] = grouped[c*TOT+n];
    #pragma unroll
    for (int c=0;c<9;c++) v[c] += g[c];
    int t=9;
    #pragma unroll
    for (int c=0;c<9;c++)
      #pragma unroll
      for (int c2=0;c2<=c;c2++){ v[t] += g[c]*g[c2]; t++; }
  }
  __shared__ float lds[4][54];
  #pragma unroll
  for (int i=0;i<54;i++){
    float r = v[i];
    #pragma unroll
    for (int off=32; off; off>>=1) r += __shfl_xor(r, off, 64);
    if (lane==0) lds[wv][i]=r;
  }
  __syncthreads();
  if (tid < 54) atomicAdd(&s0g[tid], lds[0][tid]+lds[1][tid]+lds[2][tid]+lds[3][tid]);
}

// K3: s0g -> folded BN0 coeffs; also convert W1,W2 to f16
__global__ void finalize0(const float* __restrict__ s0g,
    const float* __restrict__ W0, const float* __restrict__ g0,
    const float* __restrict__ b0, float* __restrict__ ac0,
    const float* __restrict__ W1, const float* __restrict__ W2,
    f16* __restrict__ W1h, f16* __restrict__ W2h){
  const int tid = threadIdx.x;
  __shared__ float S[54];
  if (tid < 54) S[tid] = s0g[tid];
  __syncthreads();
  if (tid < 64){
    float w[9];
    #pragma unroll
    for (int c=0;c<9;c++) w[c]=W0[tid*9+c];
    float m=0.f;
    #pragma unroll
    for (int c=0;c<9;c++) m += w[c]*S[c];
    float e2=0.f; int t=9;
    #pragma unroll
    for (int c=0;c<9;c++)
      #pragma unroll
      for (int c2=0;c2<=c;c2++){
        float x = w[c]*w[c2]*S[t++];
        e2 += (c2==c) ? x : 2.f*x;
      }
    const float inv = 1.f/(float)TOT;
    m *= inv; e2 *= inv;
    float var = e2 - m*m;
    float a = g0[tid]*rsqrtf(var + BN_EPS);
    ac0[tid]    = a;
    ac0[64+tid] = fmaf(-m, a, b0[tid]);
  }
  for (int i=tid; i<4096; i+=256) W1h[i] = (f16)W1[i];
  for (int i=tid; i<8192; i+=256) W2h[i] = (f16)W2[i];
}

// K4: x0 -> bn0+relu -> h0(f16 packed) -> x1 = h0 @ W1^T via v_dot2_f32_f16,
// stored AoS f16 [n][64].
__global__ __launch_bounds__(256) void layer1(
    const float* __restrict__ grouped, const float* __restrict__ W0,
    const f16x2* __restrict__ W1h, const float* __restrict__ ac0,
    f16x2* __restrict__ x1h){
  #pragma unroll 1
  for (int it=0; it<2; ++it){
    int n = blockIdx.x*512 + it*256 + threadIdx.x;
    float g[9];
    #pragma unroll
    for (int c=0;c<9;c++) g[c]=grouped[c*TOT+n];
    f16x2 h0p[32];
    #pragma unroll
    for (int o2=0;o2<32;o2++){
      float a=0.f, bq=0.f;
      #pragma unroll
      for (int c=0;c<9;c++){
        a  = fmaf(g[c], W0[(2*o2  )*9+c], a);
        bq = fmaf(g[c], W0[(2*o2+1)*9+c], bq);
      }
      a  = fmaxf(fmaf(a,  ac0[2*o2  ], ac0[64+2*o2  ]), 0.f);
      bq = fmaxf(fmaf(bq, ac0[2*o2+1], ac0[64+2*o2+1]), 0.f);
      f16x2 hv; hv[0]=(f16)a; hv[1]=(f16)bq;
      h0p[o2] = hv;
    }
    f16x2* outr = x1h + (size_t)n*32;
    #pragma unroll 1
    for (int o2=0;o2<32;o2++){                     // 2 output channels/iter
      const f16x2* w1a = W1h + (size_t)(2*o2  )*32;
      const f16x2* w1b = W1h + (size_t)(2*o2+1)*32;
      float a0=0.f,a1=0.f,b0=0.f,b1=0.f;
      #pragma unroll
      for (int c2=0;c2<32;c2+=2){
        a0 = fdot2(h0p[c2  ], w1a[c2  ], a0);
        a1 = fdot2(h0p[c2+1], w1a[c2+1], a1);
        b0 = fdot2(h0p[c2  ], w1b[c2  ], b0);
        b1 = fdot2(h0p[c2+1], w1b[c2+1], b1);
      }
      f16x2 xv; xv[0]=(f16)(a0+a1); xv[1]=(f16)(b0+b1);
      outr[o2] = xv;
    }
  }
}

// K5: per-channel sum/sumsq of x1 (f16 AoS), atomic into s1g[128]
__global__ __launch_bounds__(256) void stats1(const f16x8* __restrict__ x1h,
    float* __restrict__ s1g){
  const int tid=threadIdx.x;
  float s[8], qv[8];
  #pragma unroll
  for (int i=0;i<8;i++){ s[i]=0.f; qv[i]=0.f; }
  int base = blockIdx.x*256 + tid;                 // grid 512; 16 iters
  #pragma unroll 1
  for (int r=0;r<16;r++){
    f16x8 v = x1h[base + r*131072];
    #pragma unroll
    for (int i=0;i<8;i++){ float f=(float)v[i]; s[i]+=f; qv[i]=fmaf(f,f,qv[i]); }
  }
  __shared__ float lds[256][16];
  #pragma unroll
  for (int i=0;i<8;i++){ lds[tid][i]=s[i]; lds[tid][8+i]=qv[i]; }
  __syncthreads();
  if (tid < 128){
    int c = tid & 63, kind = tid>>6;
    int ph = c>>3, r = (c&7) + (kind?8:0);
    float v=0.f;
    #pragma unroll
    for (int k2=0;k2<32;k2++) v += lds[ph + k2*8][r];
    atomicAdd(&s1g[kind*64+c], v);
  }
}

// channel sums[nch]+sumsq[nch] -> folded BN coeffs
__global__ void finalizeS(const float* __restrict__ sums, int nch,
    const float* __restrict__ gg, const float* __restrict__ bb,
    float* __restrict__ ac){
  int t=threadIdx.x;
  if (t<nch){
    const float inv=1.f/(float)TOT;
    float m=sums[t]*inv;
    float v=sums[nch+t]*inv - m*m;
    float a=gg[t]*rsqrtf(v+BN_EPS);
    ac[t]=a; ac[nch+t]=fmaf(-m,a,bb[t]);
  }
}

// K6: in-place h1 = relu(a1*x1 + c1), f16
__global__ __launch_bounds__(256) void h1ify(f16x8* __restrict__ x1h,
    const float* __restrict__ ac1){
  const int tid=threadIdx.x;
  const int ph = tid & 7;
  float a[8], c[8];
  #pragma unroll
  for (int i=0;i<8;i++){ a[i]=ac1[ph*8+i]; c[i]=ac1[64+ph*8+i]; }
  int base = blockIdx.x*256+tid;                   // grid 1024; 8 iters
  #pragma unroll 1
  for (int r=0;r<8;r++){
    f16x8 v = x1h[base + r*262144];
    #pragma unroll
    for (int i=0;i<8;i++){
      float f = fmaxf(fmaf((float)v[i], a[i], c[i]), 0.f);
      v[i] = (f16)f;
    }
    x1h[base + r*262144] = v;
  }
}

// K7: x2 = h1 @ W2^T via v_dot2_f32_f16; lane = channel pair, wave-uniform
// h1 rows (scalar broadcast); per-lane max over k and sum/sumsq.
__global__ __launch_bounds__(256) void layer2max(const f16x2* __restrict__ h1,
    const f16x2* __restrict__ W2h, float* __restrict__ maxbuf,
    float* __restrict__ s2g){
  const int lane=threadIdx.x&63, wv=threadIdx.x>>6;
  const int q0 = __builtin_amdgcn_readfirstlane((blockIdx.x*4+wv)*4);
  f16x2 w2a[32], w2b[32];
  #pragma unroll
  for (int c2=0;c2<32;c2++){
    w2a[c2] = W2h[(size_t)lane*32 + c2];
    w2b[c2] = W2h[(size_t)(64+lane)*32 + c2];
  }
  float sa=0.f, sb=0.f, qa=0.f, qb=0.f;
  #pragma unroll 1
  for (int i=0;i<4;i++){
    int q = q0+i;
    const f16x2* hrow = h1 + (size_t)q*1024;       // 32 rows x 32 f16x2
    float mxa=-FLT_MAX, mxb=-FLT_MAX;
    #pragma unroll 1
    for (int k=0;k<32;k++){
      const f16x2* r = hrow + k*32;
      float a0=0.f,a1=0.f,b0=0.f,b1=0.f;
      #pragma unroll
      for (int c2=0;c2<32;c2+=2){
        f16x2 h0v = r[c2], h1v = r[c2+1];
        a0 = fdot2(h0v, w2a[c2  ], a0);
        a1 = fdot2(h1v, w2a[c2+1], a1);
        b0 = fdot2(h0v, w2b[c2  ], b0);
        b1 = fdot2(h1v, w2b[c2+1], b1);
      }
      float x=a0+a1, y=b0+b1;
      sa+=x; sb+=y; qa=fmaf(x,x,qa); qb=fmaf(y,y,qb);
      mxa=fmaxf(mxa,x); mxb=fmaxf(mxb,y);
    }
    maxbuf[q*128+lane]=mxa; maxbuf[q*128+64+lane]=mxb;
  }
  __shared__ float lds[4][256];
  lds[wv][lane]=sa; lds[wv][64+lane]=sb; lds[wv][128+lane]=qa; lds[wv][192+lane]=qb;
  __syncthreads();
  const int tid=threadIdx.x;
  float v = lds[0][tid]+lds[1][tid]+lds[2][tid]+lds[3][tid];
  atomicAdd(&s2g[tid], v);   // [0..127]=sums, [128..255]=sumsq
}

// K8: out_newpoints = relu(a2*max + c2)   (a2>0 -> commutes with max)
__global__ __launch_bounds__(256) void apply2(
    const float* __restrict__ maxbuf, const float* __restrict__ ac2,
    float* __restrict__ outp){
  int i = blockIdx.x*256 + threadIdx.x;            // 1048576
  int o = i & 127;
  outp[i] = fmaxf(fmaf(maxbuf[i], ac2[o], ac2[128+o]), 0.f);
}

extern "C" void kernel_launch(void* const* d_in, const int* in_sizes, int n_in,
                              void* d_out, int out_size, void* d_ws, size_t ws_size,
                              hipStream_t stream){
  const float* xyz = (const float*)d_in[0];
  const float* pts = (const float*)d_in[1];
  const float* W0  = (const float*)d_in[2];
  const float* g0  = (const float*)d_in[3];
  const float* b0  = (const float*)d_in[4];
  const float* W1  = (const float*)d_in[5];
  const float* g1  = (const float*)d_in[6];
  const float* b1  = (const float*)d_in[7];
  const float* W2  = (const float*)d_in[8];
  const float* g2  = (const float*)d_in[9];
  const float* b2  = (const float*)d_in[10];
  float* out = (float*)d_out;

  float* ws      = (float*)d_ws;
  float* grouped = ws;                          // 9*TOT  f32 SoA
  f16*   x1h     = (f16*)(ws + (size_t)9*TOT);  // TOT*64 f16 (=TOT*32 floats)
  float* maxbuf  = ws + (size_t)41*TOT;         // 4*TOT
  float4* xyzp   = (float4*)(ws + (size_t)45*TOT);          // 32768 float4
  f16*   W1h     = (f16*)(ws + (size_t)45*TOT + 131072);    // 4096 f16
  f16*   W2h     = W1h + 4096;                  // 8192 f16
  float* s0g     = (float*)(W2h + 8192);        // 64 (54 used)
  float* s1g     = s0g + 64;                    // 128
  float* s2g     = s1g + 128;                   // 256
  float* ac0     = s2g + 256;                   // 128
  float* ac1     = ac0 + 128;                   // 128
  float* ac2     = ac1 + 128;                   // 256

  hipMemsetAsync(s0g, 0, (64+128+256)*sizeof(float), stream);
  prep      <<< 128, 256, 0, stream>>>(xyz, xyzp);
  knn_gather<<<2048, 256, 0, stream>>>(xyzp, pts, grouped, out);
  stats0    <<< 512, 256, 0, stream>>>(grouped, s0g);
  finalize0 <<<   1, 256, 0, stream>>>(s0g, W0, g0, b0, ac0, W1, W2, W1h, W2h);
  layer1    <<< 512, 256, 0, stream>>>(grouped, W0, (const f16x2*)W1h, ac0, (f16x2*)x1h);
  stats1    <<< 512, 256, 0, stream>>>((const f16x8*)x1h, s1g);
  finalizeS <<<   1, 128, 0, stream>>>(s1g,  64, g1, b1, ac1);
  h1ify     <<<1024, 256, 0, stream>>>((f16x8*)x1h, ac1);
  layer2max <<< 512, 256, 0, stream>>>((const f16x2*)x1h, (const f16x2*)W2h, maxbuf, s2g);
  finalizeS <<<   1, 128, 0, stream>>>(s2g, 128, g2, b2, ac2);
  apply2    <<<4096, 256, 0, stream>>>(maxbuf, ac2, out + 24576);
}

// Round 5
// 231.177 us; speedup vs baseline: 4.7008x; 1.4818x over previous
//
#include <hip/hip_runtime.h>
#include <float.h>
#include <stdint.h>

// B=8, N=4096, S=1024 queries/batch, K=32 neighbors
#define TOT   262144      // 8*1024*32 grouped elements
#define NPTS  4096
#define KNN   32
#define BN_EPS 1e-5f
#define CAPV  64          // kNN fast-path candidate capacity (1 per lane)

typedef _Float16 f16;
typedef _Float16 f16x2 __attribute__((ext_vector_type(2)));
typedef _Float16 f16x4 __attribute__((ext_vector_type(4)));
typedef _Float16 f16x8 __attribute__((ext_vector_type(8)));
typedef float    f32x4 __attribute__((ext_vector_type(4)));

__device__ __forceinline__ int mbcnt64(unsigned long long m){
  return __builtin_amdgcn_mbcnt_hi((unsigned)(m>>32),
         __builtin_amdgcn_mbcnt_lo((unsigned)(m & 0xffffffffull), 0));
}
__device__ __forceinline__ unsigned f2ord(float f){
  unsigned u = __float_as_uint(f);
  return u ^ (((unsigned)((int)u >> 31)) | 0x80000000u);
}
// packed bn+relu: max(x*a+c, 0) elementwise on 2 halves (v_pk_fma + v_pk_max)
__device__ __forceinline__ f16x2 bnrelu2(f16x2 x, f16x2 a, f16x2 c){
  f16x2 r = x*a + c;
  const f16 z = (f16)0.f;
  r[0] = r[0] > z ? r[0] : z;
  r[1] = r[1] > z ? r[1] : z;
  return r;
}

// P0: xyz -> float4 {x,y,z,|p|^2}
__global__ __launch_bounds__(256) void prep(const float* __restrict__ xyz,
    float4* __restrict__ xyzp){
  int p = blockIdx.x*256 + threadIdx.x;            // 32768 points
  float x = xyz[p*3+0], y = xyz[p*3+1], z = xyz[p*3+2];
  xyzp[p] = make_float4(x, y, z, x*x+y*y+z*z);
}

// K1: one wave/query; per-lane min -> bitonic -> U bound -> compact -> u64
// bitonic sort of (key,idx) -> exact top-32 with jax.lax.top_k tie semantics.
__global__ __launch_bounds__(256) void knn_gather(
    const float4* __restrict__ xyzp, const float* __restrict__ pts,
    float* __restrict__ grouped, float* __restrict__ out_newxyz){
  __shared__ unsigned skey[4*CAPV];
  __shared__ unsigned short sidx[4*CAPV];
  const int lane = threadIdx.x & 63;
  const int wv   = threadIdx.x >> 6;
  const int q = blockIdx.x*4 + wv;                 // 0..8191
  const int b = q >> 10, s = q & 1023;
  const float4* xb = xyzp + b*NPTS;
  const float4 Q = xb[s*4];
  const float qx=Q.x, qy=Q.y, qz=Q.z, qq=Q.w;
  if (lane==0){ out_newxyz[q*3]=qx; out_newxyz[q*3+1]=qy; out_newxyz[q*3+2]=qz; }

  unsigned m = 0xFFFFFFFFu;
  #pragma unroll 8
  for (int j=0;j<64;j++){
    float4 P = xb[j*64+lane];
    float d = (qq+P.w) - 2.f*(qx*P.x+qy*P.y+qz*P.z);
    unsigned k = f2ord(d);
    m = k<m ? k : m;
  }
  unsigned sm = m;
  #pragma unroll
  for (int k=2;k<=64;k<<=1){
    #pragma unroll
    for (int j=k>>1;j>0;j>>=1){
      unsigned o = __shfl_xor(sm, j, 64);
      bool keepmin = (((lane&k)==0) == ((lane&j)==0));
      sm = keepmin ? (sm<o?sm:o) : (sm>o?sm:o);
    }
  }
  const unsigned U = __shfl(sm, 31, 64);

  unsigned* wk = skey + wv*CAPV;
  unsigned short* wi = sidx + wv*CAPV;
  int cnt = 0;
  #pragma unroll 4
  for (int j=0;j<64;j++){
    float4 P = xb[j*64+lane];
    float d = (qq+P.w) - 2.f*(qx*P.x+qy*P.y+qz*P.z);
    unsigned k = f2ord(d);
    bool sel = (k <= U);
    unsigned long long msk = __ballot(sel);
    int pos = cnt + mbcnt64(msk);
    if (sel && pos < CAPV){ wk[pos]=k; wi[pos]=(unsigned short)(j*64+lane); }
    cnt += __popcll(msk);
  }

  const float* fb = pts + (size_t)b*NPTS*6;
  const int ebase = q*KNN;
  int n = -1;

  if (cnt <= CAPV){
    unsigned myk = (lane<cnt) ? wk[lane] : 0xFFFFFFFFu;
    unsigned myi = (lane<cnt) ? wi[lane] : 0u;
    unsigned long long v = (((unsigned long long)myk)<<16) | myi;
    #pragma unroll
    for (int k=2;k<=64;k<<=1){
      #pragma unroll
      for (int j=k>>1;j>0;j>>=1){
        unsigned long long o = __shfl_xor(v, j, 64);
        bool keepmin = (((lane&k)==0) == ((lane&j)==0));
        v = keepmin ? (v<o?v:o) : (v>o?v:o);
      }
    }
    if (lane < KNN) n = (int)(v & 0xffffull);
  } else {
    unsigned V=0;
    for (int bit=31; bit>=0; --bit){
      unsigned X = V | (1u<<bit);
      int c=0;
      for (int j=0;j<64;j++){
        float4 P = xb[j*64+lane];
        float d = (qq+P.w) - 2.f*(qx*P.x+qy*P.y+qz*P.z);
        c += __popcll(__ballot(f2ord(d) < X));
      }
      if (c < KNN) V = X;
    }
    int cnt2=0;
    for (int pass=0; pass<2; ++pass){
      for (int j=0;j<64;j++){
        float4 P = xb[j*64+lane];
        float d = (qq+P.w) - 2.f*(qx*P.x+qy*P.y+qz*P.z);
        unsigned kk = f2ord(d);
        bool sel = pass ? (kk==V) : (kk<V);
        unsigned long long msk = __ballot(sel);
        int pos = cnt2 + mbcnt64(msk);
        if (sel && pos < KNN){
          int nn = j*64+lane, e = ebase+pos;
          grouped[0*TOT+e]=P.x-qx; grouped[1*TOT+e]=P.y-qy; grouped[2*TOT+e]=P.z-qz;
          for (int c6=0;c6<6;c6++) grouped[(3+c6)*TOT+e]=fb[nn*6+c6];
        }
        cnt2 += __popcll(msk);
      }
    }
  }
  if (n >= 0){
    float4 P = xb[n];
    int e = ebase + lane;
    grouped[0*TOT+e]=P.x-qx; grouped[1*TOT+e]=P.y-qy; grouped[2*TOT+e]=P.z-qz;
    #pragma unroll
    for (int c6=0;c6<6;c6++) grouped[(3+c6)*TOT+e]=fb[n*6+c6];
  }
}

// K2: E[g](9) + E[g g^T] upper tri (45), atomic-accumulated (exact f32)
__global__ __launch_bounds__(256) void stats0(
    const float* __restrict__ grouped, float* __restrict__ s0g){
  const int tid = threadIdx.x, lane = tid&63, wv = tid>>6;
  float v[54];
  #pragma unroll
  for (int i=0;i<54;i++) v[i]=0.f;
  #pragma unroll 1
  for (int it=0; it<2; ++it){
    int n = it*(512*256) + blockIdx.x*256 + tid;
    float g[9];
    #pragma unroll
    for (int c=0;c<9;c++) g[c] = grouped[c*TOT+n];
    #pragma unroll
    for (int c=0;c<9;c++) v[c] += g[c];
    int t=9;
    #pragma unroll
    for (int c=0;c<9;c++)
      #pragma unroll
      for (int c2=0;c2<=c;c2++){ v[t] += g[c]*g[c2]; t++; }
  }
  __shared__ float lds[4][54];
  #pragma unroll
  for (int i=0;i<54;i++){
    float r = v[i];
    #pragma unroll
    for (int off=32; off; off>>=1) r += __shfl_xor(r, off, 64);
    if (lane==0) lds[wv][i]=r;
  }
  __syncthreads();
  if (tid < 54) atomicAdd(&s0g[tid], lds[0][tid]+lds[1][tid]+lds[2][tid]+lds[3][tid]);
}

// K3: s0g -> BN0 coeffs; W0h = a0-folded W0 (f16, [64][32] K-padded); W1h/W2h f16
__global__ void finalize0(const float* __restrict__ s0g,
    const float* __restrict__ W0, const float* __restrict__ g0,
    const float* __restrict__ b0, float* __restrict__ ac0,
    const float* __restrict__ W1, const float* __restrict__ W2,
    f16* __restrict__ W0h, f16* __restrict__ W1h, f16* __restrict__ W2h){
  const int tid = threadIdx.x;                     // 256
  __shared__ float S[54];
  __shared__ float A0s[64];
  if (tid < 54) S[tid] = s0g[tid];
  __syncthreads();
  if (tid < 64){
    float w[9];
    #pragma unroll
    for (int c=0;c<9;c++) w[c]=W0[tid*9+c];
    float m=0.f;
    #pragma unroll
    for (int c=0;c<9;c++) m += w[c]*S[c];
    float e2=0.f; int t=9;
    #pragma unroll
    for (int c=0;c<9;c++)
      #pragma unroll
      for (int c2=0;c2<=c;c2++){
        float x = w[c]*w[c2]*S[t++];
        e2 += (c2==c) ? x : 2.f*x;
      }
    const float inv = 1.f/(float)TOT;
    m *= inv; e2 *= inv;
    float var = e2 - m*m;
    float a = g0[tid]*rsqrtf(var + BN_EPS);
    ac0[tid]    = a;
    ac0[64+tid] = fmaf(-m, a, b0[tid]);
    A0s[tid]    = a;
  }
  __syncthreads();
  for (int i=tid; i<2048; i+=256){
    int o = i>>5, c = i&31;
    W0h[i] = (f16)(c<9 ? A0s[o]*W0[o*9+c] : 0.f);
  }
  for (int i=tid; i<4096; i+=256) W1h[i] = (f16)W1[i];
  for (int i=tid; i<8192; i+=256) W2h[i] = (f16)W2[i];
}

// K4: double-MFMA layer1. GEMM1: h0pre = g @ W0'^T (K=9 padded to 32, c0 as
// C-init) -> relu -> f16 -> per-wave LDS tile [16][80] -> GEMM2: x1 = h0@W1^T.
// Orientation: A = weights (m=out ch), B = data (n=elem) -> D col = elem,
// rows = 4 consecutive out-ch per lane -> packed f16x4 stores.
__global__ __launch_bounds__(256) void layer1(
    const float* __restrict__ grouped, const f16* __restrict__ W0h,
    const f16* __restrict__ W1h, const float* __restrict__ ac0,
    f16* __restrict__ x1h){
  __shared__ f16 hb[4][16][80];                    // pad 80: 4-way max conflict
  const int lane = threadIdx.x & 63, wv = threadIdx.x >> 6;
  const int e16 = lane & 15, q = lane >> 4;
  const int base = blockIdx.x*256 + wv*64;

  f16x8 A0[4];                                     // W0h[(m*16+e16)*32 + q*8 ..]
  #pragma unroll
  for (int m=0;m<4;m++) A0[m] = *(const f16x8*)(W0h + (m*16+e16)*32 + q*8);
  f16x8 A1[4][2];                                  // W1h[(m*16+e16)*64 + s*32+q*8 ..]
  #pragma unroll
  for (int m=0;m<4;m++)
    #pragma unroll
    for (int s=0;s<2;s++) A1[m][s] = *(const f16x8*)(W1h + (m*16+e16)*64 + s*32 + q*8);
  float c0i[4][4];                                 // c0[o], o = m*16+q*4+i
  #pragma unroll
  for (int m=0;m<4;m++)
    #pragma unroll
    for (int i=0;i<4;i++) c0i[m][i] = ac0[64 + m*16 + q*4 + i];

  #pragma unroll 1
  for (int sub=0; sub<4; ++sub){
    int elem = base + sub*16 + e16;
    // GEMM1 B-frag: g[c = q*8+j][elem]; only c<9 live
    f16x8 bg = {};
    if (q==0){
      #pragma unroll
      for (int j=0;j<8;j++) bg[j] = (f16)grouped[j*TOT + elem];
    } else if (q==1){
      bg[0] = (f16)grouped[8*TOT + elem];
    }
    #pragma unroll
    for (int m=0;m<4;m++){
      f32x4 acc = {c0i[m][0], c0i[m][1], c0i[m][2], c0i[m][3]};
      acc = __builtin_amdgcn_mfma_f32_16x16x32_f16(A0[m], bg, acc, 0,0,0);
      f16x4 w;
      w[0]=(f16)fmaxf(acc[0],0.f); w[1]=(f16)fmaxf(acc[1],0.f);
      w[2]=(f16)fmaxf(acc[2],0.f); w[3]=(f16)fmaxf(acc[3],0.f);
      *(f16x4*)(&hb[wv][e16][m*16 + q*4]) = w;     // h0[elem][o]
    }
    // GEMM2 (in-wave LDS round-trip; DS ops are wave-ordered, no barrier)
    f32x4 acc2[4];
    #pragma unroll
    for (int m=0;m<4;m++) acc2[m] = (f32x4){0.f,0.f,0.f,0.f};
    #pragma unroll
    for (int s=0;s<2;s++){
      f16x8 bh = *(const f16x8*)(&hb[wv][e16][s*32 + q*8]);
      #pragma unroll
      for (int m=0;m<4;m++)
        acc2[m] = __builtin_amdgcn_mfma_f32_16x16x32_f16(A1[m][s], bh, acc2[m], 0,0,0);
    }
    #pragma unroll
    for (int m=0;m<4;m++){
      f16x4 w;
      w[0]=(f16)acc2[m][0]; w[1]=(f16)acc2[m][1];
      w[2]=(f16)acc2[m][2]; w[3]=(f16)acc2[m][3];
      *(f16x4*)(x1h + (size_t)elem*64 + m*16 + q*4) = w;
    }
  }
}

// K5: per-channel sum/sumsq of x1 (f16 AoS), atomic into s1g[128]
__global__ __launch_bounds__(256) void stats1(const f16x8* __restrict__ x1h,
    float* __restrict__ s1g){
  const int tid=threadIdx.x;
  float s[8], qv[8];
  #pragma unroll
  for (int i=0;i<8;i++){ s[i]=0.f; qv[i]=0.f; }
  int base = blockIdx.x*256 + tid;                 // grid 512; 16 iters
  #pragma unroll 1
  for (int r=0;r<16;r++){
    f16x8 v = x1h[base + r*131072];
    #pragma unroll
    for (int i=0;i<8;i++){ float f=(float)v[i]; s[i]+=f; qv[i]=fmaf(f,f,qv[i]); }
  }
  __shared__ float lds[256][16];
  #pragma unroll
  for (int i=0;i<8;i++){ lds[tid][i]=s[i]; lds[tid][8+i]=qv[i]; }
  __syncthreads();
  if (tid < 128){
    int c = tid & 63, kind = tid>>6;
    int ph = c>>3, r = (c&7) + (kind?8:0);
    float v=0.f;
    #pragma unroll
    for (int k2=0;k2<32;k2++) v += lds[ph + k2*8][r];
    atomicAdd(&s1g[kind*64+c], v);
  }
}

// channel sums[nch]+sumsq[nch] -> folded BN coeffs (+ optional f16 copy)
__global__ void finalizeS(const float* __restrict__ sums, int nch,
    const float* __restrict__ gg, const float* __restrict__ bb,
    float* __restrict__ ac, f16* __restrict__ ach){
  int t=threadIdx.x;
  if (t<nch){
    const float inv=1.f/(float)TOT;
    float m=sums[t]*inv;
    float v=sums[nch+t]*inv - m*m;
    float a=gg[t]*rsqrtf(v+BN_EPS);
    float c=fmaf(-m,a,bb[t]);
    ac[t]=a; ac[nch+t]=c;
    if (ach){ ach[t]=(f16)a; ach[nch+t]=(f16)c; }
  }
}

// K6: MFMA layer2 + max. A = h1 (m=elem, BN1+relu fused on frag load),
// B = W2 frags in regs. D rows = elems -> in-lane max + 2 cross-quad shfls.
// BN2 sums/sumsq accumulated per-lane, LDS-combined, atomics to s2g.
__global__ __launch_bounds__(256) void layer2max(const f16* __restrict__ x1h,
    const f16* __restrict__ W2h, const f16* __restrict__ ac1h,
    float* __restrict__ maxbuf, float* __restrict__ s2g){
  const int lane = threadIdx.x & 63, wv = threadIdx.x >> 6;
  const int e16 = lane & 15, q = lane >> 4;
  f16x8 Bw[8][2];                                  // W2h[(nt*16+e16)*64 + s*32+q*8 ..]
  #pragma unroll
  for (int nt=0;nt<8;nt++)
    #pragma unroll
    for (int s=0;s<2;s++) Bw[nt][s] = *(const f16x8*)(W2h + (nt*16+e16)*64 + s*32 + q*8);
  f16x2 a1p[8], c1p[8];                            // channels s*32+q*8+{0..7}
  #pragma unroll
  for (int s=0;s<2;s++)
    #pragma unroll
    for (int j2=0;j2<4;j2++){
      a1p[s*4+j2] = ((const f16x2*)ac1h)[s*16 + q*4 + j2];
      c1p[s*4+j2] = ((const f16x2*)(ac1h+64))[s*16 + q*4 + j2];
    }
  float ssum[8], ssq[8];
  #pragma unroll
  for (int i=0;i<8;i++){ ssum[i]=0.f; ssq[i]=0.f; }

  #pragma unroll 1
  for (int qq=0; qq<4; ++qq){                      // 4 queries per wave
    const int qid = blockIdx.x*16 + wv*4 + qq;
    f32x4 acc[8][2];
    #pragma unroll
    for (int nt=0;nt<8;nt++){ acc[nt][0]=(f32x4){0,0,0,0}; acc[nt][1]=(f32x4){0,0,0,0}; }
    #pragma unroll
    for (int mt=0; mt<2; ++mt){
      #pragma unroll
      for (int s=0;s<2;s++){
        f16x8 a = *(const f16x8*)(x1h + (size_t)(qid*32 + mt*16 + e16)*64 + s*32 + q*8);
        f16x2* a2 = (f16x2*)&a;
        #pragma unroll
        for (int j2=0;j2<4;j2++) a2[j2] = bnrelu2(a2[j2], a1p[s*4+j2], c1p[s*4+j2]);
        #pragma unroll
        for (int nt=0;nt<8;nt++)
          acc[nt][mt] = __builtin_amdgcn_mfma_f32_16x16x32_f16(a, Bw[nt][s], acc[nt][mt], 0,0,0);
      }
    }
    float mx[8];
    #pragma unroll
    for (int nt=0;nt<8;nt++){
      f32x4 u = acc[nt][0], v = acc[nt][1];
      float m1 = fmaxf(fmaxf(u[0],u[1]), fmaxf(u[2],u[3]));
      float m2 = fmaxf(fmaxf(v[0],v[1]), fmaxf(v[2],v[3]));
      mx[nt] = fmaxf(m1, m2);
      ssum[nt] += (u[0]+u[1])+(u[2]+u[3]) + (v[0]+v[1])+(v[2]+v[3]);
      float sq = 0.f;
      #pragma unroll
      for (int i=0;i<4;i++){ sq = fmaf(u[i],u[i],sq); sq = fmaf(v[i],v[i],sq); }
      ssq[nt] += sq;
      mx[nt] = fmaxf(mx[nt], __shfl_xor(mx[nt], 16, 64));
      mx[nt] = fmaxf(mx[nt], __shfl_xor(mx[nt], 32, 64));
    }
    if (lane < 16){
      #pragma unroll
      for (int nt=0;nt<8;nt++) maxbuf[(size_t)qid*128 + nt*16 + lane] = mx[nt];
    }
  }
  #pragma unroll
  for (int nt=0;nt<8;nt++){
    ssum[nt] += __shfl_xor(ssum[nt], 16, 64);
    ssum[nt] += __shfl_xor(ssum[nt], 32, 64);
    ssq[nt]  += __shfl_xor(ssq[nt], 16, 64);
    ssq[nt]  += __shfl_xor(ssq[nt], 32, 64);
  }
  __shared__ float lds[4][256];
  if (q==0){
    #pragma unroll
    for (int nt=0;nt<8;nt++){
      lds[wv][nt*16+e16]     = ssum[nt];
      lds[wv][128+nt*16+e16] = ssq[nt];
    }
  }
  __syncthreads();
  const int tid = threadIdx.x;
  float v = lds[0][tid]+lds[1][tid]+lds[2][tid]+lds[3][tid];
  atomicAdd(&s2g[tid], v);
}

// K7: out_newpoints = relu(a2*max + c2)   (a2>0 -> commutes with max)
__global__ __launch_bounds__(256) void apply2(
    const float* __restrict__ maxbuf, const float* __restrict__ ac2,
    float* __restrict__ outp){
  int i = blockIdx.x*256 + threadIdx.x;            // 1048576
  int o = i & 127;
  outp[i] = fmaxf(fmaf(maxbuf[i], ac2[o], ac2[128+o]), 0.f);
}

extern "C" void kernel_launch(void* const* d_in, const int* in_sizes, int n_in,
                              void* d_out, int out_size, void* d_ws, size_t ws_size,
                              hipStream_t stream){
  const float* xyz = (const float*)d_in[0];
  const float* pts = (const float*)d_in[1];
  const float* W0  = (const float*)d_in[2];
  const float* g0  = (const float*)d_in[3];
  const float* b0  = (const float*)d_in[4];
  const float* W1  = (const float*)d_in[5];
  const float* g1  = (const float*)d_in[6];
  const float* b1  = (const float*)d_in[7];
  const float* W2  = (const float*)d_in[8];
  const float* g2  = (const float*)d_in[9];
  const float* b2  = (const float*)d_in[10];
  float* out = (float*)d_out;

  float* ws      = (float*)d_ws;
  float* grouped = ws;                               // 9*TOT f32 SoA
  f16*   x1h     = (f16*)(ws + (size_t)9*TOT);       // TOT*64 f16 (32*TOT f32 eq)
  float* maxbuf  = ws + (size_t)41*TOT;              // 4*TOT
  float4* xyzp   = (float4*)(ws + (size_t)45*TOT);   // 32768 float4
  float* basep   = ws + (size_t)45*TOT + 131072;
  f16*   W0h     = (f16*)basep;                      // 2048 f16 (1024 f32)
  f16*   W1h     = (f16*)(basep + 1024);             // 4096 f16 (2048 f32)
  f16*   W2h     = (f16*)(basep + 3072);             // 8192 f16 (4096 f32)
  float* s0g     = basep + 7168;                     // 64 (54 used)
  float* s1g     = s0g + 64;                         // 128
  float* s2g     = s1g + 128;                        // 256  (contig memset)
  float* ac0     = s2g + 256;                        // 128
  float* ac1     = ac0 + 128;                        // 128
  f16*   ac1h    = (f16*)(ac1 + 128);                // 128 f16 (64 f32)
  float* ac2     = ac1 + 192;                        // 256

  (void)hipMemsetAsync(s0g, 0, (64+128+256)*sizeof(float), stream);
  prep      <<< 128, 256, 0, stream>>>(xyz, xyzp);
  knn_gather<<<2048, 256, 0, stream>>>(xyzp, pts, grouped, out);
  stats0    <<< 512, 256, 0, stream>>>(grouped, s0g);
  finalize0 <<<   1, 256, 0, stream>>>(s0g, W0, g0, b0, ac0, W1, W2, W0h, W1h, W2h);
  layer1    <<<1024, 256, 0, stream>>>(grouped, W0h, W1h, ac0, x1h);
  stats1    <<< 512, 256, 0, stream>>>((const f16x8*)x1h, s1g);
  finalizeS <<<   1, 128, 0, stream>>>(s1g,  64, g1, b1, ac1, ac1h);
  layer2max <<< 512, 256, 0, stream>>>(x1h, W2h, ac1h, maxbuf, s2g);
  finalizeS <<<   1, 128, 0, stream>>>(s2g, 128, g2, b2, ac2, (f16*)0);
  apply2    <<<4096, 256, 0, stream>>>(maxbuf, ac2, out + 24576);
}

// Round 6
// 222.346 us; speedup vs baseline: 4.8875x; 1.0397x over previous
//
#include <hip/hip_runtime.h>
#include <float.h>
#include <stdint.h>

// B=8, N=4096, S=1024 queries/batch, K=32 neighbors
#define TOT   262144      // 8*1024*32 grouped elements
#define NPTS  4096
#define KNN   32
#define BN_EPS 1e-5f
#define CAPV  64          // kNN fast-path candidate capacity (1 per lane)

typedef _Float16 f16;
typedef _Float16 f16x2 __attribute__((ext_vector_type(2)));
typedef _Float16 f16x4 __attribute__((ext_vector_type(4)));
typedef _Float16 f16x8 __attribute__((ext_vector_type(8)));
typedef float    f32x4 __attribute__((ext_vector_type(4)));

__device__ __forceinline__ unsigned f2ord(float f){
  unsigned u = __float_as_uint(f);
  return u ^ (((unsigned)((int)u >> 31)) | 0x80000000u);
}
// packed bn+relu: max(x*a+c, 0) elementwise on 2 halves (v_pk_fma + max)
__device__ __forceinline__ f16x2 bnrelu2(f16x2 x, f16x2 a, f16x2 c){
  f16x2 r = x*a + c;
  const f16 z = (f16)0.f;
  r[0] = r[0] > z ? r[0] : z;
  r[1] = r[1] > z ? r[1] : z;
  return r;
}

// P0: xyz -> float4 {x,y,z,|p|^2}
__global__ __launch_bounds__(256) void prep(const float* __restrict__ xyz,
    float4* __restrict__ xyzp){
  int p = blockIdx.x*256 + threadIdx.x;            // 32768 points
  float x = xyz[p*3+0], y = xyz[p*3+1], z = xyz[p*3+2];
  xyzp[p] = make_float4(x, y, z, x*x+y*y+z*z);
}

// K1: one wave/query; per-lane min -> bitonic -> U bound -> LDS-atomic
// compact (order-free; sort fixes it) -> u64 bitonic sort of (key,idx) ->
// exact top-32 with jax.lax.top_k tie semantics. grouped written as f16 SoA.
__global__ __launch_bounds__(256) void knn_gather(
    const float4* __restrict__ xyzp, const float* __restrict__ pts,
    f16* __restrict__ grouped, float* __restrict__ out_newxyz){
  __shared__ unsigned skey[4*CAPV];
  __shared__ unsigned short sidx[4*CAPV];
  __shared__ unsigned lcnt[4];
  const int lane = threadIdx.x & 63;
  const int wv   = threadIdx.x >> 6;
  const int q = blockIdx.x*4 + wv;                 // 0..8191
  const int b = q >> 10, s = q & 1023;
  const float4* xb = xyzp + b*NPTS;
  const float4 Q = xb[s*4];
  const float qx=Q.x, qy=Q.y, qz=Q.z, qq=Q.w;
  if (lane==0){ out_newxyz[q*3]=qx; out_newxyz[q*3+1]=qy; out_newxyz[q*3+2]=qz;
                lcnt[wv]=0; }

  // pass A: per-lane min over this lane's 64 points
  unsigned m = 0xFFFFFFFFu;
  #pragma unroll 8
  for (int j=0;j<64;j++){
    float4 P = xb[j*64+lane];
    float d = (qq+P.w) - 2.f*(qx*P.x+qy*P.y+qz*P.z);
    unsigned k = f2ord(d);
    m = k<m ? k : m;
  }
  // bitonic sort minima ascending across lanes
  unsigned sm = m;
  #pragma unroll
  for (int k=2;k<=64;k<<=1){
    #pragma unroll
    for (int j=k>>1;j>0;j>>=1){
      unsigned o = __shfl_xor(sm, j, 64);
      bool keepmin = (((lane&k)==0) == ((lane&j)==0));
      sm = keepmin ? (sm<o?sm:o) : (sm>o?sm:o);
    }
  }
  const unsigned U = __shfl(sm, 31, 64);           // 32nd smallest minimum

  // pass B: recompute keys; LDS-atomic append of candidates key<=U.
  // No loop-carried dependency (vs ballot-prefix chain). Order irrelevant.
  unsigned* wk = skey + wv*CAPV;
  unsigned short* wi = sidx + wv*CAPV;
  #pragma unroll 4
  for (int j=0;j<64;j++){
    float4 P = xb[j*64+lane];
    float d = (qq+P.w) - 2.f*(qx*P.x+qy*P.y+qz*P.z);
    unsigned k = f2ord(d);
    if (k <= U){
      unsigned p = atomicAdd(&lcnt[wv], 1u);
      if (p < CAPV){ wk[p]=k; wi[p]=(unsigned short)(j*64+lane); }
    }
  }
  int cnt = (int)lcnt[wv];                         // wave-ordered DS read

  const float* fb = pts + (size_t)b*NPTS*6;
  const int ebase = q*KNN;
  int n = -1;

  if (cnt <= CAPV){
    unsigned myk = (lane<cnt) ? wk[lane] : 0xFFFFFFFFu;
    unsigned myi = (lane<cnt) ? wi[lane] : 0u;
    unsigned long long v = (((unsigned long long)myk)<<16) | myi;
    #pragma unroll
    for (int k=2;k<=64;k<<=1){
      #pragma unroll
      for (int j=k>>1;j>0;j>>=1){
        unsigned long long o = __shfl_xor(v, j, 64);
        bool keepmin = (((lane&k)==0) == ((lane&j)==0));
        v = keepmin ? (v<o?v:o) : (v>o?v:o);
      }
    }
    if (lane < KNN) n = (int)(v & 0xffffull);
  } else {
    // slow exact path (essentially never): radix bisect + ordered collect
    unsigned V=0;
    for (int bit=31; bit>=0; --bit){
      unsigned X = V | (1u<<bit);
      int c=0;
      for (int j=0;j<64;j++){
        float4 P = xb[j*64+lane];
        float d = (qq+P.w) - 2.f*(qx*P.x+qy*P.y+qz*P.z);
        c += __popcll(__ballot(f2ord(d) < X));
      }
      if (c < KNN) V = X;
    }
    int cnt2=0;
    for (int pass=0; pass<2; ++pass){
      for (int j=0;j<64;j++){
        float4 P = xb[j*64+lane];
        float d = (qq+P.w) - 2.f*(qx*P.x+qy*P.y+qz*P.z);
        unsigned kk = f2ord(d);
        bool sel = pass ? (kk==V) : (kk<V);
        unsigned long long msk = __ballot(sel);
        int pos = cnt2 + __builtin_amdgcn_mbcnt_hi((unsigned)(msk>>32),
                  __builtin_amdgcn_mbcnt_lo((unsigned)(msk & 0xffffffffull), 0));
        if (sel && pos < KNN){
          int nn = j*64+lane, e = ebase+pos;
          grouped[0*TOT+e]=(f16)(P.x-qx); grouped[1*TOT+e]=(f16)(P.y-qy);
          grouped[2*TOT+e]=(f16)(P.z-qz);
          for (int c6=0;c6<6;c6++) grouped[(3+c6)*TOT+e]=(f16)fb[nn*6+c6];
        }
        cnt2 += __popcll(msk);
      }
    }
  }
  if (n >= 0){
    float4 P = xb[n];
    int e = ebase + lane;                          // lanes 0..31: coalesced
    grouped[0*TOT+e]=(f16)(P.x-qx); grouped[1*TOT+e]=(f16)(P.y-qy);
    grouped[2*TOT+e]=(f16)(P.z-qz);
    #pragma unroll
    for (int c6=0;c6<6;c6++) grouped[(3+c6)*TOT+e]=(f16)fb[n*6+c6];
  }
}

// K2: E[g](9) + E[g g^T] upper tri (45) from f16 grouped, atomic-accumulated
__global__ __launch_bounds__(256) void stats0(
    const f16* __restrict__ grouped, float* __restrict__ s0g){
  const int tid = threadIdx.x, lane = tid&63, wv = tid>>6;
  float v[54];
  #pragma unroll
  for (int i=0;i<54;i++) v[i]=0.f;
  #pragma unroll 1
  for (int it=0; it<2; ++it){
    int n = it*(512*256) + blockIdx.x*256 + tid;
    float g[9];
    #pragma unroll
    for (int c=0;c<9;c++) g[c] = (float)grouped[c*TOT+n];
    #pragma unroll
    for (int c=0;c<9;c++) v[c] += g[c];
    int t=9;
    #pragma unroll
    for (int c=0;c<9;c++)
      #pragma unroll
      for (int c2=0;c2<=c;c2++){ v[t] += g[c]*g[c2]; t++; }
  }
  __shared__ float lds[4][54];
  #pragma unroll
  for (int i=0;i<54;i++){
    float r = v[i];
    #pragma unroll
    for (int off=32; off; off>>=1) r += __shfl_xor(r, off, 64);
    if (lane==0) lds[wv][i]=r;
  }
  __syncthreads();
  if (tid < 54) atomicAdd(&s0g[tid], lds[0][tid]+lds[1][tid]+lds[2][tid]+lds[3][tid]);
}

// K3: s0g -> BN0 coeffs; W0h = a0-folded W0 (f16, [64][32] K-padded); W1h/W2h f16
__global__ void finalize0(const float* __restrict__ s0g,
    const float* __restrict__ W0, const float* __restrict__ g0,
    const float* __restrict__ b0, float* __restrict__ ac0,
    const float* __restrict__ W1, const float* __restrict__ W2,
    f16* __restrict__ W0h, f16* __restrict__ W1h, f16* __restrict__ W2h){
  const int tid = threadIdx.x;                     // 256
  __shared__ float S[54];
  __shared__ float A0s[64];
  if (tid < 54) S[tid] = s0g[tid];
  __syncthreads();
  if (tid < 64){
    float w[9];
    #pragma unroll
    for (int c=0;c<9;c++) w[c]=W0[tid*9+c];
    float m=0.f;
    #pragma unroll
    for (int c=0;c<9;c++) m += w[c]*S[c];
    float e2=0.f; int t=9;
    #pragma unroll
    for (int c=0;c<9;c++)
      #pragma unroll
      for (int c2=0;c2<=c;c2++){
        float x = w[c]*w[c2]*S[t++];
        e2 += (c2==c) ? x : 2.f*x;
      }
    const float inv = 1.f/(float)TOT;
    m *= inv; e2 *= inv;
    float var = e2 - m*m;
    float a = g0[tid]*rsqrtf(var + BN_EPS);
    ac0[tid]    = a;
    ac0[64+tid] = fmaf(-m, a, b0[tid]);
    A0s[tid]    = a;
  }
  __syncthreads();
  for (int i=tid; i<2048; i+=256){
    int o = i>>5, c = i&31;
    W0h[i] = (f16)(c<9 ? A0s[o]*W0[o*9+c] : 0.f);
  }
  for (int i=tid; i<4096; i+=256) W1h[i] = (f16)W1[i];
  for (int i=tid; i<8192; i+=256) W2h[i] = (f16)W2[i];
}

// K4: double-MFMA layer1 + fused BN1 stats. GEMM1: h0pre = g @ W0'^T (K=9
// padded, c0 as C-init) -> relu -> f16 -> per-wave LDS tile -> GEMM2:
// x1 = h0 @ W1^T -> f16 store + per-lane sum/sumsq accumulation (16 ch/lane),
// shfl-reduce over e16, LDS combine, 128 atomics/block into s1g.
__global__ __launch_bounds__(256) void layer1(
    const f16* __restrict__ grouped, const f16* __restrict__ W0h,
    const f16* __restrict__ W1h, const float* __restrict__ ac0,
    f16* __restrict__ x1h, float* __restrict__ s1g){
  __shared__ f16 hb[4][16][80];                    // pad 80
  __shared__ float sred[4][128];
  const int lane = threadIdx.x & 63, wv = threadIdx.x >> 6;
  const int e16 = lane & 15, q = lane >> 4;
  const int base = blockIdx.x*512 + wv*128;        // grid 512; 128 elems/wave

  f16x8 A0[4];
  #pragma unroll
  for (int m=0;m<4;m++) A0[m] = *(const f16x8*)(W0h + (m*16+e16)*32 + q*8);
  f16x8 A1[4][2];
  #pragma unroll
  for (int m=0;m<4;m++)
    #pragma unroll
    for (int s=0;s<2;s++) A1[m][s] = *(const f16x8*)(W1h + (m*16+e16)*64 + s*32 + q*8);
  float c0i[4][4];
  #pragma unroll
  for (int m=0;m<4;m++)
    #pragma unroll
    for (int i=0;i<4;i++) c0i[m][i] = ac0[64 + m*16 + q*4 + i];
  float ssum[16], ssq[16];
  #pragma unroll
  for (int i=0;i<16;i++){ ssum[i]=0.f; ssq[i]=0.f; }

  #pragma unroll 1
  for (int sub=0; sub<8; ++sub){
    int elem = base + sub*16 + e16;
    f16x8 bg = {};
    if (q==0){
      #pragma unroll
      for (int j=0;j<8;j++) bg[j] = grouped[j*TOT + elem];
    } else if (q==1){
      bg[0] = grouped[8*TOT + elem];
    }
    #pragma unroll
    for (int m=0;m<4;m++){
      f32x4 acc = {c0i[m][0], c0i[m][1], c0i[m][2], c0i[m][3]};
      acc = __builtin_amdgcn_mfma_f32_16x16x32_f16(A0[m], bg, acc, 0,0,0);
      f16x4 w;
      w[0]=(f16)fmaxf(acc[0],0.f); w[1]=(f16)fmaxf(acc[1],0.f);
      w[2]=(f16)fmaxf(acc[2],0.f); w[3]=(f16)fmaxf(acc[3],0.f);
      *(f16x4*)(&hb[wv][e16][m*16 + q*4]) = w;     // h0[elem][o]
    }
    f32x4 acc2[4];
    #pragma unroll
    for (int m=0;m<4;m++) acc2[m] = (f32x4){0.f,0.f,0.f,0.f};
    #pragma unroll
    for (int s=0;s<2;s++){
      f16x8 bh = *(const f16x8*)(&hb[wv][e16][s*32 + q*8]);
      #pragma unroll
      for (int m=0;m<4;m++)
        acc2[m] = __builtin_amdgcn_mfma_f32_16x16x32_f16(A1[m][s], bh, acc2[m], 0,0,0);
    }
    #pragma unroll
    for (int m=0;m<4;m++){
      f16x4 w;
      #pragma unroll
      for (int i=0;i<4;i++){
        float x = acc2[m][i];
        ssum[m*4+i] += x;
        ssq[m*4+i]  = fmaf(x, x, ssq[m*4+i]);
        w[i] = (f16)x;
      }
      *(f16x4*)(x1h + (size_t)elem*64 + m*16 + q*4) = w;
    }
  }
  // reduce over the 16 e16-lanes (xor bits 0..3), then combine waves
  #pragma unroll
  for (int t=0;t<16;t++){
    float a = ssum[t], bq = ssq[t];
    #pragma unroll
    for (int off=1; off<16; off<<=1){
      a  += __shfl_xor(a,  off, 64);
      bq += __shfl_xor(bq, off, 64);
    }
    ssum[t]=a; ssq[t]=bq;
  }
  if (e16==0){
    #pragma unroll
    for (int m=0;m<4;m++)
      #pragma unroll
      for (int i=0;i<4;i++){
        int ch = m*16 + q*4 + i;
        sred[wv][ch]    = ssum[m*4+i];
        sred[wv][64+ch] = ssq[m*4+i];
      }
  }
  __syncthreads();
  const int tid = threadIdx.x;
  if (tid < 128){
    float v = sred[0][tid]+sred[1][tid]+sred[2][tid]+sred[3][tid];
    atomicAdd(&s1g[tid], v);
  }
}

// channel sums[nch]+sumsq[nch] -> folded BN coeffs (+ optional f16 copy)
__global__ void finalizeS(const float* __restrict__ sums, int nch,
    const float* __restrict__ gg, const float* __restrict__ bb,
    float* __restrict__ ac, f16* __restrict__ ach){
  int t=threadIdx.x;
  if (t<nch){
    const float inv=1.f/(float)TOT;
    float m=sums[t]*inv;
    float v=sums[nch+t]*inv - m*m;
    float a=gg[t]*rsqrtf(v+BN_EPS);
    float c=fmaf(-m,a,bb[t]);
    ac[t]=a; ac[nch+t]=c;
    if (ach){ ach[t]=(f16)a; ach[nch+t]=(f16)c; }
  }
}

// K6: MFMA layer2 + max. A = h1 (m=elem, BN1+relu fused on frag load),
// B = W2 frags in regs. In-lane max + 2 cross-quad shfls; BN2 stats fused.
__global__ __launch_bounds__(256) void layer2max(const f16* __restrict__ x1h,
    const f16* __restrict__ W2h, const f16* __restrict__ ac1h,
    float* __restrict__ maxbuf, float* __restrict__ s2g){
  const int lane = threadIdx.x & 63, wv = threadIdx.x >> 6;
  const int e16 = lane & 15, q = lane >> 4;
  f16x8 Bw[8][2];
  #pragma unroll
  for (int nt=0;nt<8;nt++)
    #pragma unroll
    for (int s=0;s<2;s++) Bw[nt][s] = *(const f16x8*)(W2h + (nt*16+e16)*64 + s*32 + q*8);
  f16x2 a1p[8], c1p[8];
  #pragma unroll
  for (int s=0;s<2;s++)
    #pragma unroll
    for (int j2=0;j2<4;j2++){
      a1p[s*4+j2] = ((const f16x2*)ac1h)[s*16 + q*4 + j2];
      c1p[s*4+j2] = ((const f16x2*)(ac1h+64))[s*16 + q*4 + j2];
    }
  float ssum[8], ssq[8];
  #pragma unroll
  for (int i=0;i<8;i++){ ssum[i]=0.f; ssq[i]=0.f; }

  #pragma unroll 1
  for (int qq=0; qq<4; ++qq){                      // 4 queries per wave
    const int qid = blockIdx.x*16 + wv*4 + qq;
    f32x4 acc[8][2];
    #pragma unroll
    for (int nt=0;nt<8;nt++){ acc[nt][0]=(f32x4){0,0,0,0}; acc[nt][1]=(f32x4){0,0,0,0}; }
    #pragma unroll
    for (int mt=0; mt<2; ++mt){
      #pragma unroll
      for (int s=0;s<2;s++){
        f16x8 a = *(const f16x8*)(x1h + (size_t)(qid*32 + mt*16 + e16)*64 + s*32 + q*8);
        f16x2* a2 = (f16x2*)&a;
        #pragma unroll
        for (int j2=0;j2<4;j2++) a2[j2] = bnrelu2(a2[j2], a1p[s*4+j2], c1p[s*4+j2]);
        #pragma unroll
        for (int nt=0;nt<8;nt++)
          acc[nt][mt] = __builtin_amdgcn_mfma_f32_16x16x32_f16(a, Bw[nt][s], acc[nt][mt], 0,0,0);
      }
    }
    float mx[8];
    #pragma unroll
    for (int nt=0;nt<8;nt++){
      f32x4 u = acc[nt][0], v = acc[nt][1];
      float m1 = fmaxf(fmaxf(u[0],u[1]), fmaxf(u[2],u[3]));
      float m2 = fmaxf(fmaxf(v[0],v[1]), fmaxf(v[2],v[3]));
      mx[nt] = fmaxf(m1, m2);
      ssum[nt] += (u[0]+u[1])+(u[2]+u[3]) + (v[0]+v[1])+(v[2]+v[3]);
      float sq = 0.f;
      #pragma unroll
      for (int i=0;i<4;i++){ sq = fmaf(u[i],u[i],sq); sq = fmaf(v[i],v[i],sq); }
      ssq[nt] += sq;
      mx[nt] = fmaxf(mx[nt], __shfl_xor(mx[nt], 16, 64));
      mx[nt] = fmaxf(mx[nt], __shfl_xor(mx[nt], 32, 64));
    }
    if (lane < 16){
      #pragma unroll
      for (int nt=0;nt<8;nt++) maxbuf[(size_t)qid*128 + nt*16 + lane] = mx[nt];
    }
  }
  #pragma unroll
  for (int nt=0;nt<8;nt++){
    ssum[nt] += __shfl_xor(ssum[nt], 16, 64);
    ssum[nt] += __shfl_xor(ssum[nt], 32, 64);
    ssq[nt]  += __shfl_xor(ssq[nt], 16, 64);
    ssq[nt]  += __shfl_xor(ssq[nt], 32, 64);
  }
  __shared__ float lds[4][256];
  if (q==0){
    #pragma unroll
    for (int nt=0;nt<8;nt++){
      lds[wv][nt*16+e16]     = ssum[nt];
      lds[wv][128+nt*16+e16] = ssq[nt];
    }
  }
  __syncthreads();
  const int tid = threadIdx.x;
  float v = lds[0][tid]+lds[1][tid]+lds[2][tid]+lds[3][tid];
  atomicAdd(&s2g[tid], v);
}

// K7: out_newpoints = relu(a2*max + c2)   (a2>0 -> commutes with max)
__global__ __launch_bounds__(256) void apply2(
    const float* __restrict__ maxbuf, const float* __restrict__ ac2,
    float* __restrict__ outp){
  int i = blockIdx.x*256 + threadIdx.x;            // 1048576
  int o = i & 127;
  outp[i] = fmaxf(fmaf(maxbuf[i], ac2[o], ac2[128+o]), 0.f);
}

extern "C" void kernel_launch(void* const* d_in, const int* in_sizes, int n_in,
                              void* d_out, int out_size, void* d_ws, size_t ws_size,
                              hipStream_t stream){
  const float* xyz = (const float*)d_in[0];
  const float* pts = (const float*)d_in[1];
  const float* W0  = (const float*)d_in[2];
  const float* g0  = (const float*)d_in[3];
  const float* b0  = (const float*)d_in[4];
  const float* W1  = (const float*)d_in[5];
  const float* g1  = (const float*)d_in[6];
  const float* b1  = (const float*)d_in[7];
  const float* W2  = (const float*)d_in[8];
  const float* g2  = (const float*)d_in[9];
  const float* b2  = (const float*)d_in[10];
  float* out = (float*)d_out;

  float* ws      = (float*)d_ws;
  f16*   grouped = (f16*)ws;                         // 9*TOT f16 (5*TOT f32)
  f16*   x1h     = (f16*)(ws + (size_t)5*TOT);       // 64*TOT f16 (32*TOT f32)
  float* maxbuf  = ws + (size_t)37*TOT;              // 4*TOT
  float4* xyzp   = (float4*)(ws + (size_t)41*TOT);   // 32768 float4
  float* basep   = ws + (size_t)41*TOT + 131072;
  f16*   W0h     = (f16*)basep;                      // 2048 f16
  f16*   W1h     = (f16*)(basep + 1024);             // 4096 f16
  f16*   W2h     = (f16*)(basep + 3072);             // 8192 f16
  float* s0g     = basep + 7168;                     // 64 (54 used)
  float* s1g     = s0g + 64;                         // 128
  float* s2g     = s1g + 128;                        // 256  (contig memset)
  float* ac0     = s2g + 256;                        // 128
  float* ac1     = ac0 + 128;                        // 128
  f16*   ac1h    = (f16*)(ac1 + 128);                // 128 f16
  float* ac2     = ac1 + 192;                        // 256

  (void)hipMemsetAsync(s0g, 0, (64+128+256)*sizeof(float), stream);
  prep      <<< 128, 256, 0, stream>>>(xyz, xyzp);
  knn_gather<<<2048, 256, 0, stream>>>(xyzp, pts, grouped, out);
  stats0    <<< 512, 256, 0, stream>>>(grouped, s0g);
  finalize0 <<<   1, 256, 0, stream>>>(s0g, W0, g0, b0, ac0, W1, W2, W0h, W1h, W2h);
  layer1    <<< 512, 256, 0, stream>>>(grouped, W0h, W1h, ac0, x1h, s1g);
  finalizeS <<<   1, 128, 0, stream>>>(s1g,  64, g1, b1, ac1, ac1h);
  layer2max <<< 512, 256, 0, stream>>>(x1h, W2h, ac1h, maxbuf, s2g);
  finalizeS <<<   1, 128, 0, stream>>>(s2g, 128, g2, b2, ac2, (f16*)0);
  apply2    <<<4096, 256, 0, stream>>>(maxbuf, ac2, out + 24576);
}